// Round 1
// baseline (31269.775 us; speedup 1.0000x reference)
//
#include <hip/hip_runtime.h>
#include <hip/hip_bf16.h>

#define DEV __device__ __forceinline__

typedef __bf16 bf16x8 __attribute__((ext_vector_type(8)));
typedef __bf16 bf16x4 __attribute__((ext_vector_type(4)));
typedef float  f32x4  __attribute__((ext_vector_type(4)));

constexpr int BB  = 512;   // batch
constexpr int TT  = 256;   // time steps
constexpr int DX  = 1024;
constexpr int DZ  = 256;
constexpr int DH  = 512;
constexpr int DDZ = 256;
constexpr int DDX = 256;

DEV f32x4 mfma16(bf16x8 a, bf16x8 b, f32x4 c) {
    // D[m][n] = sum_k A[m][k]*B[k][n]; A lane: m=l&15,k=8*(l>>4)+i; B lane: n=l&15,k=8*(l>>4)+i
    // D lane: col=l&15, row=4*(l>>4)+reg
    return __builtin_amdgcn_mfma_f32_16x16x32_bf16(a, b, c, 0, 0, 0);
}
DEV float sigf(float x) { return 1.0f / (1.0f + __expf(-x)); }
DEV float tanhf_(float x) {
    float e = __expf(-2.0f * fabsf(x));
    float r = (1.0f - e) / (1.0f + e);
    return copysignf(r, x);
}
DEV float softplusf(float x) {
    float m = fmaxf(x, 0.0f);
    return m + __logf(__expf(x - m) + __expf(-m));
}

// ---------------- weight fp32 -> bf16 conversion ----------------
struct CvtArgs {
    const float* src[7];
    __bf16* dst[7];
    int n[7];
};
__global__ void cvt_weights(CvtArgs a) {
    for (int s = 0; s < 7; ++s) {
        const float* sp = a.src[s];
        __bf16* dp = a.dst[s];
        int n = a.n[s];
        for (int i = blockIdx.x * blockDim.x + threadIdx.x; i < n; i += gridDim.x * blockDim.x)
            dp[i] = (__bf16)sp[i];
    }
}

// ---------------- phase 1: sequential recurrence ----------------
// 32 blocks x 512 threads (8 waves). Block owns 16 batch rows; no inter-block sync.
// h_t (fp32) is stashed into out[b][t][0:DH]; phase 2 overwrites all of out.
__global__ __launch_bounds__(512, 2) void phase1(
    const float* __restrict__ eps,
    const float* __restrict__ b1,  const float* __restrict__ bloc,
    const float* __restrict__ bscale, const float* __restrict__ bih,
    const float* __restrict__ bhh, const float* __restrict__ h0,
    const __bf16* __restrict__ wW1,   const __bf16* __restrict__ wWloc,
    const __bf16* __restrict__ wWscale, const __bf16* __restrict__ wWih,
    const __bf16* __restrict__ wWhh,
    float* __restrict__ out)
{
    __shared__ __bf16 h_bf [16 * 512];   // swizzled, MFMA A source
    __shared__ float  h_f32[16 * 512];   // exact recurrent state
    __shared__ __bf16 hid_bf[16 * 256];  // swizzled
    __shared__ __bf16 z_bf [16 * 256];   // swizzled

    const int tid  = threadIdx.x;
    const int w    = tid >> 6;
    const int lane = tid & 63;
    const int r16  = lane & 15;
    const int g4   = lane >> 4;
    const int b0   = blockIdx.x * 16;

    // init h = h0 (broadcast over rows)
    for (int e = tid; e < 16 * 512; e += 512) {
        int row = e >> 9;
        float v = h0[e & 511];
        h_f32[e] = v;
        h_bf[e ^ ((row & 7) << 3)] = (__bf16)v;
    }
    __syncthreads();

    const int hidN = w * 32;   // hid/z col base (2 tiles of 16)
    const int hc0  = w * 64;   // h-col slice for gates (4 tiles of 16)

    // persistent weight row pointers (lane-dependent)
    const __bf16* pW1a = wW1 + (hidN + r16) * 512 + g4 * 8;
    const __bf16* pW1b = wW1 + (hidN + 16 + r16) * 512 + g4 * 8;
    const __bf16* pWhh[12];
    const __bf16* pWih[12];
    #pragma unroll
    for (int g = 0; g < 3; ++g)
        #pragma unroll
        for (int ct = 0; ct < 4; ++ct) {
            int n = g * 512 + hc0 + 16 * ct + r16;
            pWhh[g * 4 + ct] = wWhh + n * 512 + g4 * 8;
            pWih[g * 4 + ct] = wWih + n * 256 + g4 * 8;
        }
    const __bf16* pLoc0 = wWloc   + (hidN + r16) * 256 + g4 * 8;
    const __bf16* pLoc1 = wWloc   + (hidN + 16 + r16) * 256 + g4 * 8;
    const __bf16* pScl0 = wWscale + (hidN + r16) * 256 + g4 * 8;
    const __bf16* pScl1 = wWscale + (hidN + 16 + r16) * 256 + g4 * 8;

    for (int t = 0; t < TT; ++t) {
        // ---- S1: hid = relu(h @ W1^T + b1) ; gh = h @ Whh^T  (both need only h)
        f32x4 accH0 = {0,0,0,0}, accH1 = {0,0,0,0};
        f32x4 accGH[12];
        #pragma unroll
        for (int m = 0; m < 12; ++m) accGH[m] = (f32x4){0,0,0,0};
        #pragma unroll
        for (int kk = 0; kk < 16; ++kk) {
            int e = (r16 * 512 + kk * 32 + g4 * 8) ^ ((r16 & 7) << 3);
            bf16x8 a = *(const bf16x8*)(h_bf + e);
            accH0 = mfma16(a, *(const bf16x8*)(pW1a + kk * 32), accH0);
            accH1 = mfma16(a, *(const bf16x8*)(pW1b + kk * 32), accH1);
            #pragma unroll
            for (int m = 0; m < 12; ++m)
                accGH[m] = mfma16(a, *(const bf16x8*)(pWhh[m] + kk * 32), accGH[m]);
        }
        {
            int c0 = hidN + r16, c1 = hidN + 16 + r16;
            float bb0 = b1[c0], bb1 = b1[c1];
            #pragma unroll
            for (int i = 0; i < 4; ++i) {
                int row = g4 * 4 + i;
                int sw = (row & 7) << 3;
                hid_bf[(row * 256 + c0) ^ sw] = (__bf16)fmaxf(accH0[i] + bb0, 0.0f);
                hid_bf[(row * 256 + c1) ^ sw] = (__bf16)fmaxf(accH1[i] + bb1, 0.0f);
            }
        }
        __syncthreads();

        // ---- S2: z = zloc + softplus(zscale) * eps_t
        f32x4 accL0 = {0,0,0,0}, accL1 = {0,0,0,0};
        f32x4 accS0 = {0,0,0,0}, accS1 = {0,0,0,0};
        #pragma unroll
        for (int kk = 0; kk < 8; ++kk) {
            int e = (r16 * 256 + kk * 32 + g4 * 8) ^ ((r16 & 7) << 3);
            bf16x8 a = *(const bf16x8*)(hid_bf + e);
            accL0 = mfma16(a, *(const bf16x8*)(pLoc0 + kk * 32), accL0);
            accL1 = mfma16(a, *(const bf16x8*)(pLoc1 + kk * 32), accL1);
            accS0 = mfma16(a, *(const bf16x8*)(pScl0 + kk * 32), accS0);
            accS1 = mfma16(a, *(const bf16x8*)(pScl1 + kk * 32), accS1);
        }
        {
            int c0 = hidN + r16, c1 = hidN + 16 + r16;
            float bl0 = bloc[c0], bl1 = bloc[c1];
            float bs0 = bscale[c0], bs1 = bscale[c1];
            #pragma unroll
            for (int i = 0; i < 4; ++i) {
                int row = g4 * 4 + i;
                int sw = (row & 7) << 3;
                size_t ebase = ((size_t)(b0 + row) * TT + t) * DZ;
                float e0 = eps[ebase + c0];
                float e1 = eps[ebase + c1];
                float z0 = (accL0[i] + bl0) + softplusf(accS0[i] + bs0) * e0;
                float z1 = (accL1[i] + bl1) + softplusf(accS1[i] + bs1) * e1;
                z_bf[(row * 256 + c0) ^ sw] = (__bf16)z0;
                z_bf[(row * 256 + c1) ^ sw] = (__bf16)z1;
            }
        }
        __syncthreads();

        // ---- S3: gi = z @ Wih^T ; gates ; h_new
        f32x4 accGI[12];
        #pragma unroll
        for (int m = 0; m < 12; ++m) accGI[m] = (f32x4){0,0,0,0};
        #pragma unroll
        for (int kk = 0; kk < 8; ++kk) {
            int e = (r16 * 256 + kk * 32 + g4 * 8) ^ ((r16 & 7) << 3);
            bf16x8 a = *(const bf16x8*)(z_bf + e);
            #pragma unroll
            for (int m = 0; m < 12; ++m)
                accGI[m] = mfma16(a, *(const bf16x8*)(pWih[m] + kk * 32), accGI[m]);
        }
        #pragma unroll
        for (int ct = 0; ct < 4; ++ct) {
            int col = hc0 + 16 * ct + r16;
            float bir = bih[col],        bhr = bhh[col];
            float biu = bih[512 + col],  bhu = bhh[512 + col];
            float bin = bih[1024 + col], bhn = bhh[1024 + col];
            #pragma unroll
            for (int i = 0; i < 4; ++i) {
                int row = g4 * 4 + i;
                float ir = accGI[0 * 4 + ct][i] + bir, hr = accGH[0 * 4 + ct][i] + bhr;
                float iu = accGI[1 * 4 + ct][i] + biu, hu = accGH[1 * 4 + ct][i] + bhu;
                float in_ = accGI[2 * 4 + ct][i] + bin, hn_ = accGH[2 * 4 + ct][i] + bhn;
                float r = sigf(ir + hr);
                float u = sigf(iu + hu);
                float nn = tanhf_(in_ + r * hn_);
                float hold = h_f32[row * 512 + col];
                float hv = (1.0f - u) * nn + u * hold;
                h_f32[row * 512 + col] = hv;
                h_bf[(row * 512 + col) ^ ((row & 7) << 3)] = (__bf16)hv;
                // stash h_t for phase 2 into out[b][t][0:DH]
                out[((size_t)(b0 + row) * TT + t) * DX + col] = hv;
            }
        }
        __syncthreads();
    }
}

// ---------------- phase 2: emitter (fully parallel over B*T) ----------------
// 4096 blocks x 256 threads (4 waves). Block owns 32 flat rows of (b,t).
// Reads h from out[row][0:512] (written by phase 1), overwrites out[row][0:1024].
__global__ __launch_bounds__(256, 3) void phase2(
    const float* __restrict__ db1, const float* __restrict__ db2,
    const __bf16* __restrict__ W1, const __bf16* __restrict__ W2,
    float* __restrict__ out)
{
    __shared__ __bf16 hS  [32 * 512];   // 32 KB, swizzled
    __shared__ __bf16 hid2[32 * 256];   // 16 KB, swizzled

    const int tid  = threadIdx.x;
    const int w    = tid >> 6;
    const int lane = tid & 63;
    const int r16  = lane & 15;
    const int g4   = lane >> 4;
    const size_t row0 = (size_t)blockIdx.x * 32;

    // stage h rows (fp32 in out) -> bf16 LDS (swizzled)
    #pragma unroll
    for (int it = 0; it < 16; ++it) {
        int e4 = (it * 256 + tid) * 4;      // element index, 4 at a time
        int row = e4 >> 9;
        int col = e4 & 511;
        const float4 v = *(const float4*)(out + (row0 + row) * DX + col);
        bf16x4 b;
        b[0] = (__bf16)v.x; b[1] = (__bf16)v.y; b[2] = (__bf16)v.z; b[3] = (__bf16)v.w;
        *(bf16x4*)(hS + ((row * 512 + col) ^ ((row & 7) << 3))) = b;
    }
    __syncthreads();

    // stage A: hid2 = relu(h @ dxW1^T + b1)   [32 x 256], K=512
    {
        f32x4 acc[2][4];
        #pragma unroll
        for (int rt = 0; rt < 2; ++rt)
            #pragma unroll
            for (int ct = 0; ct < 4; ++ct) acc[rt][ct] = (f32x4){0,0,0,0};
        const __bf16* pB[4];
        #pragma unroll
        for (int ct = 0; ct < 4; ++ct)
            pB[ct] = W1 + (w * 64 + 16 * ct + r16) * 512 + g4 * 8;
        #pragma unroll
        for (int kk = 0; kk < 16; ++kk) {
            bf16x8 a[2];
            #pragma unroll
            for (int rt = 0; rt < 2; ++rt) {
                int row = rt * 16 + r16;
                a[rt] = *(const bf16x8*)(hS + ((row * 512 + kk * 32 + g4 * 8) ^ ((row & 7) << 3)));
            }
            #pragma unroll
            for (int ct = 0; ct < 4; ++ct) {
                bf16x8 b = *(const bf16x8*)(pB[ct] + kk * 32);
                acc[0][ct] = mfma16(a[0], b, acc[0][ct]);
                acc[1][ct] = mfma16(a[1], b, acc[1][ct]);
            }
        }
        #pragma unroll
        for (int ct = 0; ct < 4; ++ct) {
            int col = w * 64 + 16 * ct + r16;
            float bias = db1[col];
            #pragma unroll
            for (int rt = 0; rt < 2; ++rt)
                #pragma unroll
                for (int i = 0; i < 4; ++i) {
                    int row = rt * 16 + g4 * 4 + i;
                    hid2[(row * 256 + col) ^ ((row & 7) << 3)] =
                        (__bf16)fmaxf(acc[rt][ct][i] + bias, 0.0f);
                }
        }
    }
    __syncthreads();

    // stage B: x = sigmoid(hid2 @ dxW2^T + b2)   [32 x 1024], K=256
    #pragma unroll
    for (int c = 0; c < 4; ++c) {
        f32x4 acc[2][4];
        #pragma unroll
        for (int rt = 0; rt < 2; ++rt)
            #pragma unroll
            for (int ct = 0; ct < 4; ++ct) acc[rt][ct] = (f32x4){0,0,0,0};
        const __bf16* pB[4];
        #pragma unroll
        for (int ct = 0; ct < 4; ++ct)
            pB[ct] = W2 + (w * 256 + c * 64 + 16 * ct + r16) * 256 + g4 * 8;
        #pragma unroll
        for (int kk = 0; kk < 8; ++kk) {
            bf16x8 a[2];
            #pragma unroll
            for (int rt = 0; rt < 2; ++rt) {
                int row = rt * 16 + r16;
                a[rt] = *(const bf16x8*)(hid2 + ((row * 256 + kk * 32 + g4 * 8) ^ ((row & 7) << 3)));
            }
            #pragma unroll
            for (int ct = 0; ct < 4; ++ct) {
                bf16x8 b = *(const bf16x8*)(pB[ct] + kk * 32);
                acc[0][ct] = mfma16(a[0], b, acc[0][ct]);
                acc[1][ct] = mfma16(a[1], b, acc[1][ct]);
            }
        }
        #pragma unroll
        for (int ct = 0; ct < 4; ++ct) {
            int col = w * 256 + c * 64 + 16 * ct + r16;
            float bias = db2[col];
            #pragma unroll
            for (int rt = 0; rt < 2; ++rt)
                #pragma unroll
                for (int i = 0; i < 4; ++i) {
                    int row = rt * 16 + g4 * 4 + i;
                    out[(row0 + row) * DX + col] = sigf(acc[rt][ct][i] + bias);
                }
        }
    }
}

// ---------------- launch ----------------
extern "C" void kernel_launch(void* const* d_in, const int* in_sizes, int n_in,
                              void* d_out, int out_size, void* d_ws, size_t ws_size,
                              hipStream_t stream) {
    const float* eps       = (const float*)d_in[0];
    const float* dz_W1     = (const float*)d_in[1];
    const float* dz_b1     = (const float*)d_in[2];
    const float* dz_Wloc   = (const float*)d_in[3];
    const float* dz_bloc   = (const float*)d_in[4];
    const float* dz_Wscale = (const float*)d_in[5];
    const float* dz_bscale = (const float*)d_in[6];
    const float* gru_Wih   = (const float*)d_in[7];
    const float* gru_Whh   = (const float*)d_in[8];
    const float* gru_bih   = (const float*)d_in[9];
    const float* gru_bhh   = (const float*)d_in[10];
    const float* dx_W1     = (const float*)d_in[11];
    const float* dx_b1     = (const float*)d_in[12];
    const float* dx_W2     = (const float*)d_in[13];
    const float* dx_b2     = (const float*)d_in[14];
    const float* h0        = (const float*)d_in[15];
    float* out = (float*)d_out;
    char* ws = (char*)d_ws;

    __bf16* wW1     = (__bf16*)(ws + 0);        // 256x512  -> 262144 B
    __bf16* wWloc   = (__bf16*)(ws + 262144);   // 256x256  -> 131072 B
    __bf16* wWscale = (__bf16*)(ws + 393216);   // 256x256  -> 131072 B
    __bf16* wWih    = (__bf16*)(ws + 524288);   // 1536x256 -> 786432 B
    __bf16* wWhh    = (__bf16*)(ws + 1310720);  // 1536x512 -> 1572864 B
    __bf16* wdxW1   = (__bf16*)(ws + 2883584);  // 256x512  -> 262144 B
    __bf16* wdxW2   = (__bf16*)(ws + 3145728);  // 1024x256 -> 524288 B

    CvtArgs ca;
    ca.src[0] = dz_W1;     ca.dst[0] = wW1;     ca.n[0] = DDZ * DH;
    ca.src[1] = dz_Wloc;   ca.dst[1] = wWloc;   ca.n[1] = DZ * DDZ;
    ca.src[2] = dz_Wscale; ca.dst[2] = wWscale; ca.n[2] = DZ * DDZ;
    ca.src[3] = gru_Wih;   ca.dst[3] = wWih;    ca.n[3] = 3 * DH * DZ;
    ca.src[4] = gru_Whh;   ca.dst[4] = wWhh;    ca.n[4] = 3 * DH * DH;
    ca.src[5] = dx_W1;     ca.dst[5] = wdxW1;   ca.n[5] = DDX * DH;
    ca.src[6] = dx_W2;     ca.dst[6] = wdxW2;   ca.n[6] = DX * DDX;

    cvt_weights<<<1024, 256, 0, stream>>>(ca);
    phase1<<<BB / 16, 512, 0, stream>>>(eps, dz_b1, dz_bloc, dz_bscale,
                                        gru_bih, gru_bhh, h0,
                                        wW1, wWloc, wWscale, wWih, wWhh, out);
    phase2<<<(BB * TT) / 32, 256, 0, stream>>>(dx_b1, dx_b2, wdxW1, wdxW2, out);
}

// Round 2
// 31256.979 us; speedup vs baseline: 1.0004x; 1.0004x over previous
//
#include <hip/hip_runtime.h>
#include <hip/hip_bf16.h>

#define DEV __device__ __forceinline__

typedef __bf16 bf16x8 __attribute__((ext_vector_type(8)));
typedef __bf16 bf16x4 __attribute__((ext_vector_type(4)));
typedef float  f32x4  __attribute__((ext_vector_type(4)));

constexpr int BB  = 512;   // batch
constexpr int TT  = 256;   // time steps
constexpr int DX  = 1024;
constexpr int DZ  = 256;
constexpr int DH  = 512;
constexpr int DDZ = 256;
constexpr int DDX = 256;

DEV f32x4 mfma16(bf16x8 a, bf16x8 b, f32x4 c) {
    // D[m][n] = sum_k A[m][k]*B[k][n]; A lane: m=l&15,k=8*(l>>4)+i; B lane: n=l&15,k=8*(l>>4)+i
    // D lane: col=l&15, row=4*(l>>4)+reg
    return __builtin_amdgcn_mfma_f32_16x16x32_bf16(a, b, c, 0, 0, 0);
}
DEV float sigf(float x) { return 1.0f / (1.0f + __expf(-x)); }
DEV float tanhf_(float x) {
    float e = __expf(-2.0f * fabsf(x));
    float r = (1.0f - e) / (1.0f + e);
    return copysignf(r, x);
}
DEV float softplusf(float x) {
    float m = fmaxf(x, 0.0f);
    return m + __logf(__expf(x - m) + __expf(-m));
}

// ---------------- weight fp32 -> bf16 conversion ----------------
struct CvtArgs {
    const float* src[7];
    __bf16* dst[7];
    int n[7];
};
__global__ void cvt_weights(CvtArgs a) {
    for (int s = 0; s < 7; ++s) {
        const float* sp = a.src[s];
        __bf16* dp = a.dst[s];
        int n = a.n[s];
        for (int i = blockIdx.x * blockDim.x + threadIdx.x; i < n; i += gridDim.x * blockDim.x)
            dp[i] = (__bf16)sp[i];
    }
}

// ---------------- phase 1: sequential recurrence ----------------
// 32 blocks x 512 threads (8 waves). Block owns 16 batch rows; no inter-block sync.
// h_t (fp32) is stashed into out[b][t][0:DH]; phase 2 overwrites all of out.
// Streaming traffic (eps in, h-stash out) uses NONTEMPORAL ops so the 2.88 MB
// of bf16 weights stays resident in each XCD's 4 MB L2 across all 256 steps.
__global__ __launch_bounds__(512, 2) void phase1(
    const float* __restrict__ eps,
    const float* __restrict__ b1,  const float* __restrict__ bloc,
    const float* __restrict__ bscale, const float* __restrict__ bih,
    const float* __restrict__ bhh, const float* __restrict__ h0,
    const __bf16* __restrict__ wW1,   const __bf16* __restrict__ wWloc,
    const __bf16* __restrict__ wWscale, const __bf16* __restrict__ wWih,
    const __bf16* __restrict__ wWhh,
    float* __restrict__ out)
{
    __shared__ __bf16 h_bf [16 * 512];   // swizzled, MFMA A source
    __shared__ float  h_f32[16 * 512];   // exact recurrent state
    __shared__ __bf16 hid_bf[16 * 256];  // swizzled
    __shared__ __bf16 z_bf [16 * 256];   // swizzled

    const int tid  = threadIdx.x;
    const int w    = tid >> 6;
    const int lane = tid & 63;
    const int r16  = lane & 15;
    const int g4   = lane >> 4;
    const int b0   = blockIdx.x * 16;

    // init h = h0 (broadcast over rows)
    for (int e = tid; e < 16 * 512; e += 512) {
        int row = e >> 9;
        float v = h0[e & 511];
        h_f32[e] = v;
        h_bf[e ^ ((row & 7) << 3)] = (__bf16)v;
    }
    __syncthreads();

    const int hidN = w * 32;   // hid/z col base (2 tiles of 16)
    const int hc0  = w * 64;   // h-col slice for gates (4 tiles of 16)

    // persistent weight row pointers (lane-dependent)
    const __bf16* pW1a = wW1 + (hidN + r16) * 512 + g4 * 8;
    const __bf16* pW1b = wW1 + (hidN + 16 + r16) * 512 + g4 * 8;
    const __bf16* pWhh[12];
    const __bf16* pWih[12];
    #pragma unroll
    for (int g = 0; g < 3; ++g)
        #pragma unroll
        for (int ct = 0; ct < 4; ++ct) {
            int n = g * 512 + hc0 + 16 * ct + r16;
            pWhh[g * 4 + ct] = wWhh + n * 512 + g4 * 8;
            pWih[g * 4 + ct] = wWih + n * 256 + g4 * 8;
        }
    const __bf16* pLoc0 = wWloc   + (hidN + r16) * 256 + g4 * 8;
    const __bf16* pLoc1 = wWloc   + (hidN + 16 + r16) * 256 + g4 * 8;
    const __bf16* pScl0 = wWscale + (hidN + r16) * 256 + g4 * 8;
    const __bf16* pScl1 = wWscale + (hidN + 16 + r16) * 256 + g4 * 8;

    for (int t = 0; t < TT; ++t) {
        // ---- S1: hid = relu(h @ W1^T + b1) ; gh = h @ Whh^T  (both need only h)
        f32x4 accH0 = {0,0,0,0}, accH1 = {0,0,0,0};
        f32x4 accGH[12];
        #pragma unroll
        for (int m = 0; m < 12; ++m) accGH[m] = (f32x4){0,0,0,0};
        #pragma unroll
        for (int kk = 0; kk < 16; ++kk) {
            int e = (r16 * 512 + kk * 32 + g4 * 8) ^ ((r16 & 7) << 3);
            bf16x8 a = *(const bf16x8*)(h_bf + e);
            accH0 = mfma16(a, *(const bf16x8*)(pW1a + kk * 32), accH0);
            accH1 = mfma16(a, *(const bf16x8*)(pW1b + kk * 32), accH1);
            #pragma unroll
            for (int m = 0; m < 12; ++m)
                accGH[m] = mfma16(a, *(const bf16x8*)(pWhh[m] + kk * 32), accGH[m]);
        }
        {
            int c0 = hidN + r16, c1 = hidN + 16 + r16;
            float bb0 = b1[c0], bb1 = b1[c1];
            #pragma unroll
            for (int i = 0; i < 4; ++i) {
                int row = g4 * 4 + i;
                int sw = (row & 7) << 3;
                hid_bf[(row * 256 + c0) ^ sw] = (__bf16)fmaxf(accH0[i] + bb0, 0.0f);
                hid_bf[(row * 256 + c1) ^ sw] = (__bf16)fmaxf(accH1[i] + bb1, 0.0f);
            }
        }
        __syncthreads();

        // ---- S2: z = zloc + softplus(zscale) * eps_t
        f32x4 accL0 = {0,0,0,0}, accL1 = {0,0,0,0};
        f32x4 accS0 = {0,0,0,0}, accS1 = {0,0,0,0};
        #pragma unroll
        for (int kk = 0; kk < 8; ++kk) {
            int e = (r16 * 256 + kk * 32 + g4 * 8) ^ ((r16 & 7) << 3);
            bf16x8 a = *(const bf16x8*)(hid_bf + e);
            accL0 = mfma16(a, *(const bf16x8*)(pLoc0 + kk * 32), accL0);
            accL1 = mfma16(a, *(const bf16x8*)(pLoc1 + kk * 32), accL1);
            accS0 = mfma16(a, *(const bf16x8*)(pScl0 + kk * 32), accS0);
            accS1 = mfma16(a, *(const bf16x8*)(pScl1 + kk * 32), accS1);
        }
        {
            int c0 = hidN + r16, c1 = hidN + 16 + r16;
            float bl0 = bloc[c0], bl1 = bloc[c1];
            float bs0 = bscale[c0], bs1 = bscale[c1];
            #pragma unroll
            for (int i = 0; i < 4; ++i) {
                int row = g4 * 4 + i;
                int sw = (row & 7) << 3;
                size_t ebase = ((size_t)(b0 + row) * TT + t) * DZ;
                float e0 = __builtin_nontemporal_load(eps + ebase + c0);
                float e1 = __builtin_nontemporal_load(eps + ebase + c1);
                float z0 = (accL0[i] + bl0) + softplusf(accS0[i] + bs0) * e0;
                float z1 = (accL1[i] + bl1) + softplusf(accS1[i] + bs1) * e1;
                z_bf[(row * 256 + c0) ^ sw] = (__bf16)z0;
                z_bf[(row * 256 + c1) ^ sw] = (__bf16)z1;
            }
        }
        __syncthreads();

        // ---- S3: gi = z @ Wih^T ; gates ; h_new
        f32x4 accGI[12];
        #pragma unroll
        for (int m = 0; m < 12; ++m) accGI[m] = (f32x4){0,0,0,0};
        #pragma unroll
        for (int kk = 0; kk < 8; ++kk) {
            int e = (r16 * 256 + kk * 32 + g4 * 8) ^ ((r16 & 7) << 3);
            bf16x8 a = *(const bf16x8*)(z_bf + e);
            #pragma unroll
            for (int m = 0; m < 12; ++m)
                accGI[m] = mfma16(a, *(const bf16x8*)(pWih[m] + kk * 32), accGI[m]);
        }
        #pragma unroll
        for (int ct = 0; ct < 4; ++ct) {
            int col = hc0 + 16 * ct + r16;
            float bir = bih[col],        bhr = bhh[col];
            float biu = bih[512 + col],  bhu = bhh[512 + col];
            float bin = bih[1024 + col], bhn = bhh[1024 + col];
            #pragma unroll
            for (int i = 0; i < 4; ++i) {
                int row = g4 * 4 + i;
                float ir = accGI[0 * 4 + ct][i] + bir, hr = accGH[0 * 4 + ct][i] + bhr;
                float iu = accGI[1 * 4 + ct][i] + biu, hu = accGH[1 * 4 + ct][i] + bhu;
                float in_ = accGI[2 * 4 + ct][i] + bin, hn_ = accGH[2 * 4 + ct][i] + bhn;
                float r = sigf(ir + hr);
                float u = sigf(iu + hu);
                float nn = tanhf_(in_ + r * hn_);
                float hold = h_f32[row * 512 + col];
                float hv = (1.0f - u) * nn + u * hold;
                h_f32[row * 512 + col] = hv;
                h_bf[(row * 512 + col) ^ ((row & 7) << 3)] = (__bf16)hv;
                // stash h_t for phase 2 into out[b][t][0:DH] (streaming -> nt)
                __builtin_nontemporal_store(hv, out + ((size_t)(b0 + row) * TT + t) * DX + col);
            }
        }
        __syncthreads();
    }
}

// ---------------- phase 2: emitter (fully parallel over B*T) ----------------
// 4096 blocks x 256 threads (4 waves). Block owns 32 flat rows of (b,t).
// Reads h from out[row][0:512] (written by phase 1), overwrites out[row][0:1024].
// h reads and x stores are streaming (read-once/write-once) -> nontemporal, so
// the 0.77 MB of emitter weights stays L2-resident across 4096 blocks.
__global__ __launch_bounds__(256, 3) void phase2(
    const float* __restrict__ db1, const float* __restrict__ db2,
    const __bf16* __restrict__ W1, const __bf16* __restrict__ W2,
    float* __restrict__ out)
{
    __shared__ __bf16 hS  [32 * 512];   // 32 KB, swizzled
    __shared__ __bf16 hid2[32 * 256];   // 16 KB, swizzled

    const int tid  = threadIdx.x;
    const int w    = tid >> 6;
    const int lane = tid & 63;
    const int r16  = lane & 15;
    const int g4   = lane >> 4;
    const size_t row0 = (size_t)blockIdx.x * 32;

    // stage h rows (fp32 in out) -> bf16 LDS (swizzled)
    #pragma unroll
    for (int it = 0; it < 16; ++it) {
        int e4 = (it * 256 + tid) * 4;      // element index, 4 at a time
        int row = e4 >> 9;
        int col = e4 & 511;
        const f32x4 v = __builtin_nontemporal_load(
            (const f32x4*)(out + (row0 + row) * DX + col));
        bf16x4 b;
        b[0] = (__bf16)v[0]; b[1] = (__bf16)v[1]; b[2] = (__bf16)v[2]; b[3] = (__bf16)v[3];
        *(bf16x4*)(hS + ((row * 512 + col) ^ ((row & 7) << 3))) = b;
    }
    __syncthreads();

    // stage A: hid2 = relu(h @ dxW1^T + b1)   [32 x 256], K=512
    {
        f32x4 acc[2][4];
        #pragma unroll
        for (int rt = 0; rt < 2; ++rt)
            #pragma unroll
            for (int ct = 0; ct < 4; ++ct) acc[rt][ct] = (f32x4){0,0,0,0};
        const __bf16* pB[4];
        #pragma unroll
        for (int ct = 0; ct < 4; ++ct)
            pB[ct] = W1 + (w * 64 + 16 * ct + r16) * 512 + g4 * 8;
        #pragma unroll
        for (int kk = 0; kk < 16; ++kk) {
            bf16x8 a[2];
            #pragma unroll
            for (int rt = 0; rt < 2; ++rt) {
                int row = rt * 16 + r16;
                a[rt] = *(const bf16x8*)(hS + ((row * 512 + kk * 32 + g4 * 8) ^ ((row & 7) << 3)));
            }
            #pragma unroll
            for (int ct = 0; ct < 4; ++ct) {
                bf16x8 b = *(const bf16x8*)(pB[ct] + kk * 32);
                acc[0][ct] = mfma16(a[0], b, acc[0][ct]);
                acc[1][ct] = mfma16(a[1], b, acc[1][ct]);
            }
        }
        #pragma unroll
        for (int ct = 0; ct < 4; ++ct) {
            int col = w * 64 + 16 * ct + r16;
            float bias = db1[col];
            #pragma unroll
            for (int rt = 0; rt < 2; ++rt)
                #pragma unroll
                for (int i = 0; i < 4; ++i) {
                    int row = rt * 16 + g4 * 4 + i;
                    hid2[(row * 256 + col) ^ ((row & 7) << 3)] =
                        (__bf16)fmaxf(acc[rt][ct][i] + bias, 0.0f);
                }
        }
    }
    __syncthreads();

    // stage B: x = sigmoid(hid2 @ dxW2^T + b2)   [32 x 1024], K=256
    #pragma unroll
    for (int c = 0; c < 4; ++c) {
        f32x4 acc[2][4];
        #pragma unroll
        for (int rt = 0; rt < 2; ++rt)
            #pragma unroll
            for (int ct = 0; ct < 4; ++ct) acc[rt][ct] = (f32x4){0,0,0,0};
        const __bf16* pB[4];
        #pragma unroll
        for (int ct = 0; ct < 4; ++ct)
            pB[ct] = W2 + (w * 256 + c * 64 + 16 * ct + r16) * 256 + g4 * 8;
        #pragma unroll
        for (int kk = 0; kk < 8; ++kk) {
            bf16x8 a[2];
            #pragma unroll
            for (int rt = 0; rt < 2; ++rt) {
                int row = rt * 16 + r16;
                a[rt] = *(const bf16x8*)(hid2 + ((row * 256 + kk * 32 + g4 * 8) ^ ((row & 7) << 3)));
            }
            #pragma unroll
            for (int ct = 0; ct < 4; ++ct) {
                bf16x8 b = *(const bf16x8*)(pB[ct] + kk * 32);
                acc[0][ct] = mfma16(a[0], b, acc[0][ct]);
                acc[1][ct] = mfma16(a[1], b, acc[1][ct]);
            }
        }
        #pragma unroll
        for (int ct = 0; ct < 4; ++ct) {
            int col = w * 256 + c * 64 + 16 * ct + r16;
            float bias = db2[col];
            #pragma unroll
            for (int rt = 0; rt < 2; ++rt)
                #pragma unroll
                for (int i = 0; i < 4; ++i) {
                    int row = rt * 16 + g4 * 4 + i;
                    __builtin_nontemporal_store(sigf(acc[rt][ct][i] + bias),
                                                out + (row0 + row) * DX + col);
                }
        }
    }
}

// ---------------- launch ----------------
extern "C" void kernel_launch(void* const* d_in, const int* in_sizes, int n_in,
                              void* d_out, int out_size, void* d_ws, size_t ws_size,
                              hipStream_t stream) {
    const float* eps       = (const float*)d_in[0];
    const float* dz_W1     = (const float*)d_in[1];
    const float* dz_b1     = (const float*)d_in[2];
    const float* dz_Wloc   = (const float*)d_in[3];
    const float* dz_bloc   = (const float*)d_in[4];
    const float* dz_Wscale = (const float*)d_in[5];
    const float* dz_bscale = (const float*)d_in[6];
    const float* gru_Wih   = (const float*)d_in[7];
    const float* gru_Whh   = (const float*)d_in[8];
    const float* gru_bih   = (const float*)d_in[9];
    const float* gru_bhh   = (const float*)d_in[10];
    const float* dx_W1     = (const float*)d_in[11];
    const float* dx_b1     = (const float*)d_in[12];
    const float* dx_W2     = (const float*)d_in[13];
    const float* dx_b2     = (const float*)d_in[14];
    const float* h0        = (const float*)d_in[15];
    float* out = (float*)d_out;
    char* ws = (char*)d_ws;

    __bf16* wW1     = (__bf16*)(ws + 0);        // 256x512  -> 262144 B
    __bf16* wWloc   = (__bf16*)(ws + 262144);   // 256x256  -> 131072 B
    __bf16* wWscale = (__bf16*)(ws + 393216);   // 256x256  -> 131072 B
    __bf16* wWih    = (__bf16*)(ws + 524288);   // 1536x256 -> 786432 B
    __bf16* wWhh    = (__bf16*)(ws + 1310720);  // 1536x512 -> 1572864 B
    __bf16* wdxW1   = (__bf16*)(ws + 2883584);  // 256x512  -> 262144 B
    __bf16* wdxW2   = (__bf16*)(ws + 3145728);  // 1024x256 -> 524288 B

    CvtArgs ca;
    ca.src[0] = dz_W1;     ca.dst[0] = wW1;     ca.n[0] = DDZ * DH;
    ca.src[1] = dz_Wloc;   ca.dst[1] = wWloc;   ca.n[1] = DZ * DDZ;
    ca.src[2] = dz_Wscale; ca.dst[2] = wWscale; ca.n[2] = DZ * DDZ;
    ca.src[3] = gru_Wih;   ca.dst[3] = wWih;    ca.n[3] = 3 * DH * DZ;
    ca.src[4] = gru_Whh;   ca.dst[4] = wWhh;    ca.n[4] = 3 * DH * DH;
    ca.src[5] = dx_W1;     ca.dst[5] = wdxW1;   ca.n[5] = DDX * DH;
    ca.src[6] = dx_W2;     ca.dst[6] = wdxW2;   ca.n[6] = DX * DDX;

    cvt_weights<<<1024, 256, 0, stream>>>(ca);
    phase1<<<BB / 16, 512, 0, stream>>>(eps, dz_b1, dz_bloc, dz_bscale,
                                        gru_bih, gru_bhh, h0,
                                        wW1, wWloc, wWscale, wWih, wWhh, out);
    phase2<<<(BB * TT) / 32, 256, 0, stream>>>(dx_b1, dx_b2, wdxW1, wdxW2, out);
}

// Round 3
// 4771.581 us; speedup vs baseline: 6.5533x; 6.5507x over previous
//
#include <hip/hip_runtime.h>
#include <hip/hip_bf16.h>

#define DEV __device__ __forceinline__

typedef __bf16 bf16x8 __attribute__((ext_vector_type(8)));
typedef __bf16 bf16x4 __attribute__((ext_vector_type(4)));
typedef float  f32x4  __attribute__((ext_vector_type(4)));

constexpr int BB  = 512;   // batch
constexpr int TT  = 256;   // time steps
constexpr int DX  = 1024;
constexpr int DZ  = 256;
constexpr int DH  = 512;

DEV f32x4 mfma16(bf16x8 a, bf16x8 b, f32x4 c) {
    // D[m][n] = sum_k A[m][k]*B[k][n]; A lane: m=l&15,k=8*(l>>4)+i; B lane: n=l&15,k=8*(l>>4)+i
    // D lane: col=l&15, row=4*(l>>4)+reg
    return __builtin_amdgcn_mfma_f32_16x16x32_bf16(a, b, c, 0, 0, 0);
}
DEV float sigf(float x) { return 1.0f / (1.0f + __expf(-x)); }
DEV float tanhf_(float x) {
    float e = __expf(-2.0f * fabsf(x));
    float r = (1.0f - e) / (1.0f + e);
    return copysignf(r, x);
}
DEV float softplusf(float x) {
    float m = fmaxf(x, 0.0f);
    return m + __logf(__expf(x - m) + __expf(-m));
}

// group barrier helpers: monotone counters, zeroed by hipMemsetAsync each call.
DEV void wait_ge(unsigned* ctr, unsigned target) {
    if (threadIdx.x == 0) {
        while (__hip_atomic_load(ctr, __ATOMIC_RELAXED, __HIP_MEMORY_SCOPE_AGENT) < target)
            __builtin_amdgcn_s_sleep(1);
        __builtin_amdgcn_fence(__ATOMIC_ACQUIRE, "agent");
    }
    __syncthreads();
}
DEV void signal_ctr(unsigned* ctr) {
    __syncthreads();   // drain all block stores to L2 first
    if (threadIdx.x == 0)
        __hip_atomic_fetch_add(ctr, 1u, __ATOMIC_RELEASE, __HIP_MEMORY_SCOPE_AGENT);
}

// ---------------- weight fp32 -> bf16 conversion ----------------
struct CvtArgs {
    const float* src[7];
    __bf16* dst[7];
    int n[7];
};
__global__ void cvt_weights(CvtArgs a) {
    for (int s = 0; s < 7; ++s) {
        const float* sp = a.src[s];
        __bf16* dp = a.dst[s];
        int n = a.n[s];
        for (int i = blockIdx.x * blockDim.x + threadIdx.x; i < n; i += gridDim.x * blockDim.x)
            dp[i] = (__bf16)sp[i];
    }
}

// ---------------- phase 1: cooperative weight-stationary recurrence ----------
// 192 blocks x 256 threads. 8 groups (group = bid&7 -> one XCD under round-robin
// dispatch; correctness does NOT depend on placement). Group owns 64 batch rows.
// rank r = bid>>3: r<8 -> Z-block (hid+z producer), r>=8 -> G-block (gates/h').
// Weight slices live in LDS for all 256 steps; only activations move (via the
// group's XCD-local L2). 3 group barriers per step; h_bf double-buffered.
__global__ __launch_bounds__(256, 1) void phase1c(
    const float* __restrict__ eps,
    const float* __restrict__ b1,  const float* __restrict__ bloc,
    const float* __restrict__ bscale, const float* __restrict__ bih,
    const float* __restrict__ bhh, const float* __restrict__ h0,
    const __bf16* __restrict__ wW1,   const __bf16* __restrict__ wWloc,
    const __bf16* __restrict__ wWscale, const __bf16* __restrict__ wWih,
    const __bf16* __restrict__ wWhh,
    __bf16* __restrict__ h_bf,      // [2][512][512] double-buffered
    __bf16* __restrict__ hid_bf,    // [512][256]
    __bf16* __restrict__ z_bf,      // [512][256]
    unsigned* __restrict__ ctrs,    // 3 phases x 8 groups, 128B stride
    float* __restrict__ out)
{
    __shared__ __bf16 lds[73728];   // 144 KB (gfx950 LDS=160KB)

    const int tid  = threadIdx.x;
    const int w    = tid >> 6;
    const int lane = tid & 63;
    const int r16  = lane & 15;
    const int g4   = lane >> 4;
    const int g    = blockIdx.x & 7;
    const int r    = blockIdx.x >> 3;     // 0..23
    unsigned* ctrA = ctrs + (0 * 8 + g) * 32;
    unsigned* ctrB = ctrs + (1 * 8 + g) * 32;
    unsigned* ctrC = ctrs + (2 * 8 + g) * 32;
    const int rowB = g * 64 + w * 16;     // wave's global batch-row base
    constexpr int HBUF = 512 * 512;       // elems per h buffer

    // ---- stage weight slices into LDS (swizzled: elem ^= (localrow&7)<<3) ----
    auto stage = [&](const __bf16* src, __bf16* dst, int R, int C) {
        int chunks = R * C / 8;
        for (int ch = tid; ch < chunks; ch += 256) {
            int row = ch / (C / 8);
            int cc  = (ch % (C / 8)) * 8;
            bf16x8 v = *(const bf16x8*)(src + row * C + cc);
            *(bf16x8*)(dst + ((row * C + cc) ^ ((row & 7) << 3))) = v;
        }
    };

    float hreg[2][4];          // G: fp32 recurrent state (own 32 cols x 4 rows)
    float bI[3][2], bH[3][2];  // G biases
    float bb1[2], bbl[2], bbs[2]; // Z biases

    if (r < 8) {
        stage(wW1     + (r * 32) * 512, lds,         32, 512);  // 32 KB
        stage(wWloc   + (r * 32) * 256, lds + 16384, 32, 256);  // 16 KB
        stage(wWscale + (r * 32) * 256, lds + 24576, 32, 256);  // 16 KB
        #pragma unroll
        for (int tt = 0; tt < 2; ++tt) {
            int c = r * 32 + tt * 16 + r16;
            bb1[tt] = b1[c]; bbl[tt] = bloc[c]; bbs[tt] = bscale[c];
        }
        __syncthreads();
    } else {
        int c0 = (r - 8) * 32;
        for (int gg = 0; gg < 3; ++gg) {
            stage(wWhh + (512 * gg + c0) * 512, lds + (gg * 32) * 512, 32, 512);      // 96 KB
            stage(wWih + (512 * gg + c0) * 256, lds + 49152 + (gg * 32) * 256, 32, 256); // 48 KB
        }
        #pragma unroll
        for (int gg = 0; gg < 3; ++gg)
            #pragma unroll
            for (int tt = 0; tt < 2; ++tt) {
                int col = 512 * gg + c0 + tt * 16 + r16;
                bI[gg][tt] = bih[col];
                bH[gg][tt] = bhh[col];
            }
        // init h = h0 into buffer 0 (own cols), and registers
        #pragma unroll
        for (int tt = 0; tt < 2; ++tt) {
            int col = c0 + tt * 16 + r16;
            float v = h0[col];
            #pragma unroll
            for (int i = 0; i < 4; ++i) {
                hreg[tt][i] = v;
                h_bf[(rowB + 4 * g4 + i) * 512 + col] = (__bf16)v;
            }
        }
        signal_ctr(ctrA);   // contributes to ctrA=16 (h_0 ready)
    }

    if (r < 8) {
        // ================= Z-block =================
        const int zc0 = r * 32;
        for (int t = 0; t < TT; ++t) {
            wait_ge(ctrA, 16u * (t + 1));
            const __bf16* hb = h_bf + (t & 1) * HBUF;
            // phase A: hid slice = relu(h @ W1^T + b1), cols [zc0, zc0+32)
            f32x4 acc[2] = {{0,0,0,0},{0,0,0,0}};
            #pragma unroll
            for (int kk = 0; kk < 16; ++kk) {
                bf16x8 a = *(const bf16x8*)(hb + (rowB + r16) * 512 + kk * 32 + g4 * 8);
                #pragma unroll
                for (int tt = 0; tt < 2; ++tt) {
                    int lr = tt * 16 + r16;
                    bf16x8 b = *(const bf16x8*)(lds + ((lr * 512 + kk * 32 + g4 * 8) ^ ((lr & 7) << 3)));
                    acc[tt] = mfma16(a, b, acc[tt]);
                }
            }
            #pragma unroll
            for (int tt = 0; tt < 2; ++tt) {
                int col = zc0 + tt * 16 + r16;
                #pragma unroll
                for (int i = 0; i < 4; ++i)
                    hid_bf[(rowB + 4 * g4 + i) * 256 + col] =
                        (__bf16)fmaxf(acc[tt][i] + bb1[tt], 0.0f);
            }
            signal_ctr(ctrB);
            wait_ge(ctrB, 8u * (t + 1));
            // phase B: z slice = zloc + softplus(zscale)*eps, cols [zc0, zc0+32)
            f32x4 aL[2] = {{0,0,0,0},{0,0,0,0}};
            f32x4 aS[2] = {{0,0,0,0},{0,0,0,0}};
            #pragma unroll
            for (int kk = 0; kk < 8; ++kk) {
                bf16x8 a = *(const bf16x8*)(hid_bf + (rowB + r16) * 256 + kk * 32 + g4 * 8);
                #pragma unroll
                for (int tt = 0; tt < 2; ++tt) {
                    int lr = tt * 16 + r16;
                    int sw = (lr * 256 + kk * 32 + g4 * 8) ^ ((lr & 7) << 3);
                    aL[tt] = mfma16(a, *(const bf16x8*)(lds + 16384 + sw), aL[tt]);
                    aS[tt] = mfma16(a, *(const bf16x8*)(lds + 24576 + sw), aS[tt]);
                }
            }
            #pragma unroll
            for (int tt = 0; tt < 2; ++tt) {
                int col = zc0 + tt * 16 + r16;
                #pragma unroll
                for (int i = 0; i < 4; ++i) {
                    int row = rowB + 4 * g4 + i;
                    float e = __builtin_nontemporal_load(eps + ((size_t)row * TT + t) * DZ + col);
                    float z = (aL[tt][i] + bbl[tt]) + softplusf(aS[tt][i] + bbs[tt]) * e;
                    z_bf[row * 256 + col] = (__bf16)z;
                }
            }
            signal_ctr(ctrC);
        }
    } else {
        // ================= G-block =================
        const int c0 = (r - 8) * 32;
        for (int t = 0; t < TT; ++t) {
            wait_ge(ctrA, 16u * (t + 1));
            const __bf16* hb = h_bf + (t & 1) * HBUF;
            __bf16* hw = h_bf + ((t + 1) & 1) * HBUF;
            // phase A: gh = h @ Whh_slice^T  [16 rows/wave x 96 cols], j = gate*2+tt
            f32x4 gh[6];
            #pragma unroll
            for (int j = 0; j < 6; ++j) gh[j] = (f32x4){0,0,0,0};
            #pragma unroll
            for (int kk = 0; kk < 16; ++kk) {
                bf16x8 a = *(const bf16x8*)(hb + (rowB + r16) * 512 + kk * 32 + g4 * 8);
                #pragma unroll
                for (int j = 0; j < 6; ++j) {
                    int lr = j * 16 + r16;
                    bf16x8 b = *(const bf16x8*)(lds + ((lr * 512 + kk * 32 + g4 * 8) ^ ((lr & 7) << 3)));
                    gh[j] = mfma16(a, b, gh[j]);
                }
            }
            wait_ge(ctrC, 8u * (t + 1));
            // phase C: gi = z @ Wih_slice^T
            f32x4 gi[6];
            #pragma unroll
            for (int j = 0; j < 6; ++j) gi[j] = (f32x4){0,0,0,0};
            #pragma unroll
            for (int kk = 0; kk < 8; ++kk) {
                bf16x8 a = *(const bf16x8*)(z_bf + (rowB + r16) * 256 + kk * 32 + g4 * 8);
                #pragma unroll
                for (int j = 0; j < 6; ++j) {
                    int lr = j * 16 + r16;
                    bf16x8 b = *(const bf16x8*)(lds + 49152 + ((lr * 256 + kk * 32 + g4 * 8) ^ ((lr & 7) << 3)));
                    gi[j] = mfma16(a, b, gi[j]);
                }
            }
            // gates + h' (h state lives in fp32 registers of this block)
            #pragma unroll
            for (int tt = 0; tt < 2; ++tt) {
                int col = c0 + tt * 16 + r16;
                #pragma unroll
                for (int i = 0; i < 4; ++i) {
                    int row = rowB + 4 * g4 + i;
                    float rr = sigf(gi[0 + tt][i] + bI[0][tt] + gh[0 + tt][i] + bH[0][tt]);
                    float uu = sigf(gi[2 + tt][i] + bI[1][tt] + gh[2 + tt][i] + bH[1][tt]);
                    float nn = tanhf_(gi[4 + tt][i] + bI[2][tt] + rr * (gh[4 + tt][i] + bH[2][tt]));
                    float hv = (1.0f - uu) * nn + uu * hreg[tt][i];
                    hreg[tt][i] = hv;
                    hw[row * 512 + col] = (__bf16)hv;   // next step's MFMA A source
                    // stash h_t for phase 2 (streaming)
                    __builtin_nontemporal_store(hv, out + ((size_t)row * TT + t) * DX + col);
                }
            }
            signal_ctr(ctrA);
        }
    }
}

// ---------------- phase 2: emitter (fully parallel over B*T) ----------------
__global__ __launch_bounds__(256, 3) void phase2(
    const float* __restrict__ db1, const float* __restrict__ db2,
    const __bf16* __restrict__ W1, const __bf16* __restrict__ W2,
    float* __restrict__ out)
{
    __shared__ __bf16 hS  [32 * 512];   // 32 KB, swizzled
    __shared__ __bf16 hid2[32 * 256];   // 16 KB, swizzled

    const int tid  = threadIdx.x;
    const int w    = tid >> 6;
    const int lane = tid & 63;
    const int r16  = lane & 15;
    const int g4   = lane >> 4;
    const size_t row0 = (size_t)blockIdx.x * 32;

    #pragma unroll
    for (int it = 0; it < 16; ++it) {
        int e4 = (it * 256 + tid) * 4;
        int row = e4 >> 9;
        int col = e4 & 511;
        const f32x4 v = __builtin_nontemporal_load(
            (const f32x4*)(out + (row0 + row) * DX + col));
        bf16x4 b;
        b[0] = (__bf16)v[0]; b[1] = (__bf16)v[1]; b[2] = (__bf16)v[2]; b[3] = (__bf16)v[3];
        *(bf16x4*)(hS + ((row * 512 + col) ^ ((row & 7) << 3))) = b;
    }
    __syncthreads();

    {   // hid2 = relu(h @ dxW1^T + b1)   [32 x 256], K=512
        f32x4 acc[2][4];
        #pragma unroll
        for (int rt = 0; rt < 2; ++rt)
            #pragma unroll
            for (int ct = 0; ct < 4; ++ct) acc[rt][ct] = (f32x4){0,0,0,0};
        const __bf16* pB[4];
        #pragma unroll
        for (int ct = 0; ct < 4; ++ct)
            pB[ct] = W1 + (w * 64 + 16 * ct + r16) * 512 + g4 * 8;
        #pragma unroll
        for (int kk = 0; kk < 16; ++kk) {
            bf16x8 a[2];
            #pragma unroll
            for (int rt = 0; rt < 2; ++rt) {
                int row = rt * 16 + r16;
                a[rt] = *(const bf16x8*)(hS + ((row * 512 + kk * 32 + g4 * 8) ^ ((row & 7) << 3)));
            }
            #pragma unroll
            for (int ct = 0; ct < 4; ++ct) {
                bf16x8 b = *(const bf16x8*)(pB[ct] + kk * 32);
                acc[0][ct] = mfma16(a[0], b, acc[0][ct]);
                acc[1][ct] = mfma16(a[1], b, acc[1][ct]);
            }
        }
        #pragma unroll
        for (int ct = 0; ct < 4; ++ct) {
            int col = w * 64 + 16 * ct + r16;
            float bias = db1[col];
            #pragma unroll
            for (int rt = 0; rt < 2; ++rt)
                #pragma unroll
                for (int i = 0; i < 4; ++i) {
                    int row = rt * 16 + g4 * 4 + i;
                    hid2[(row * 256 + col) ^ ((row & 7) << 3)] =
                        (__bf16)fmaxf(acc[rt][ct][i] + bias, 0.0f);
                }
        }
    }
    __syncthreads();

    #pragma unroll
    for (int c = 0; c < 4; ++c) {   // x = sigmoid(hid2 @ dxW2^T + b2) [32 x 1024]
        f32x4 acc[2][4];
        #pragma unroll
        for (int rt = 0; rt < 2; ++rt)
            #pragma unroll
            for (int ct = 0; ct < 4; ++ct) acc[rt][ct] = (f32x4){0,0,0,0};
        const __bf16* pB[4];
        #pragma unroll
        for (int ct = 0; ct < 4; ++ct)
            pB[ct] = W2 + (w * 256 + c * 64 + 16 * ct + r16) * 256 + g4 * 8;
        #pragma unroll
        for (int kk = 0; kk < 8; ++kk) {
            bf16x8 a[2];
            #pragma unroll
            for (int rt = 0; rt < 2; ++rt) {
                int row = rt * 16 + r16;
                a[rt] = *(const bf16x8*)(hid2 + ((row * 256 + kk * 32 + g4 * 8) ^ ((row & 7) << 3)));
            }
            #pragma unroll
            for (int ct = 0; ct < 4; ++ct) {
                bf16x8 b = *(const bf16x8*)(pB[ct] + kk * 32);
                acc[0][ct] = mfma16(a[0], b, acc[0][ct]);
                acc[1][ct] = mfma16(a[1], b, acc[1][ct]);
            }
        }
        #pragma unroll
        for (int ct = 0; ct < 4; ++ct) {
            int col = w * 256 + c * 64 + 16 * ct + r16;
            float bias = db2[col];
            #pragma unroll
            for (int rt = 0; rt < 2; ++rt)
                #pragma unroll
                for (int i = 0; i < 4; ++i) {
                    int row = rt * 16 + g4 * 4 + i;
                    __builtin_nontemporal_store(sigf(acc[rt][ct][i] + bias),
                                                out + (row0 + row) * DX + col);
                }
        }
    }
}

// ---------------- launch ----------------
extern "C" void kernel_launch(void* const* d_in, const int* in_sizes, int n_in,
                              void* d_out, int out_size, void* d_ws, size_t ws_size,
                              hipStream_t stream) {
    const float* eps       = (const float*)d_in[0];
    const float* dz_W1     = (const float*)d_in[1];
    const float* dz_b1     = (const float*)d_in[2];
    const float* dz_Wloc   = (const float*)d_in[3];
    const float* dz_bloc   = (const float*)d_in[4];
    const float* dz_Wscale = (const float*)d_in[5];
    const float* dz_bscale = (const float*)d_in[6];
    const float* gru_Wih   = (const float*)d_in[7];
    const float* gru_Whh   = (const float*)d_in[8];
    const float* gru_bih   = (const float*)d_in[9];
    const float* gru_bhh   = (const float*)d_in[10];
    const float* dx_W1     = (const float*)d_in[11];
    const float* dx_b1     = (const float*)d_in[12];
    const float* dx_W2     = (const float*)d_in[13];
    const float* dx_b2     = (const float*)d_in[14];
    const float* h0        = (const float*)d_in[15];
    float* out = (float*)d_out;
    char* ws = (char*)d_ws;

    __bf16* wW1     = (__bf16*)(ws + 0);        // 256x512
    __bf16* wWloc   = (__bf16*)(ws + 262144);   // 256x256
    __bf16* wWscale = (__bf16*)(ws + 393216);   // 256x256
    __bf16* wWih    = (__bf16*)(ws + 524288);   // 1536x256
    __bf16* wWhh    = (__bf16*)(ws + 1310720);  // 1536x512
    __bf16* wdxW1   = (__bf16*)(ws + 2883584);  // 256x512
    __bf16* wdxW2   = (__bf16*)(ws + 3145728);  // 1024x256
    // activation exchange buffers
    __bf16*  h_bf   = (__bf16*)(ws + 3670016);  // 2 x 512x512 bf16 = 1 MB
    __bf16*  hid_bf = (__bf16*)(ws + 4718592);  // 512x256 = 256 KB
    __bf16*  z_bf   = (__bf16*)(ws + 4980736);  // 512x256 = 256 KB
    unsigned* ctrs  = (unsigned*)(ws + 5242880); // 3x8 counters, 128B stride (4 KB)

    hipMemsetAsync(ctrs, 0, 4096, stream);

    CvtArgs ca;
    ca.src[0] = dz_W1;     ca.dst[0] = wW1;     ca.n[0] = 256 * 512;
    ca.src[1] = dz_Wloc;   ca.dst[1] = wWloc;   ca.n[1] = 256 * 256;
    ca.src[2] = dz_Wscale; ca.dst[2] = wWscale; ca.n[2] = 256 * 256;
    ca.src[3] = gru_Wih;   ca.dst[3] = wWih;    ca.n[3] = 1536 * 256;
    ca.src[4] = gru_Whh;   ca.dst[4] = wWhh;    ca.n[4] = 1536 * 512;
    ca.src[5] = dx_W1;     ca.dst[5] = wdxW1;   ca.n[5] = 256 * 512;
    ca.src[6] = dx_W2;     ca.dst[6] = wdxW2;   ca.n[6] = 1024 * 256;

    cvt_weights<<<1024, 256, 0, stream>>>(ca);
    phase1c<<<192, 256, 0, stream>>>(eps, dz_b1, dz_bloc, dz_bscale,
                                     gru_bih, gru_bhh, h0,
                                     wW1, wWloc, wWscale, wWih, wWhh,
                                     h_bf, hid_bf, z_bf, ctrs, out);
    phase2<<<(BB * TT) / 32, 256, 0, stream>>>(dx_b1, dx_b2, wdxW1, wdxW2, out);
}

// Round 5
// 3855.165 us; speedup vs baseline: 8.1111x; 1.2377x over previous
//
#include <hip/hip_runtime.h>
#include <hip/hip_bf16.h>

#define DEV __device__ __forceinline__

typedef __bf16 bf16x8 __attribute__((ext_vector_type(8)));
typedef float  f32x4  __attribute__((ext_vector_type(4)));

constexpr int BB  = 512;   // batch
constexpr int TT  = 256;   // time steps
constexpr int DX  = 1024;
constexpr int DZ  = 256;
constexpr int DH  = 512;

DEV f32x4 mfma16(bf16x8 a, bf16x8 b, f32x4 c) {
    return __builtin_amdgcn_mfma_f32_16x16x32_bf16(a, b, c, 0, 0, 0);
}
DEV float sigf(float x) { return 1.0f / (1.0f + __expf(-x)); }
DEV float tanhf_(float x) {
    float e = __expf(-2.0f * fabsf(x));
    float r = (1.0f - e) / (1.0f + e);
    return copysignf(r, x);
}
DEV float softplusf(float x) {
    float m = fmaxf(x, 0.0f);
    return m + __logf(__expf(x - m) + __expf(-m));
}

// ---- device-coherent (sc0 sc1) write-through ops ----
DEV void st16_wt(void* p, bf16x8 v) {
    asm volatile("global_store_dwordx4 %0, %1, off sc0 sc1" :: "v"(p), "v"(v) : "memory");
}
DEV void st2_wt(void* p, unsigned short v) {
    asm volatile("global_store_short %0, %1, off sc0 sc1" :: "v"(p), "v"(v) : "memory");
}
DEV void st_flag(unsigned* p, unsigned v) {
    asm volatile("global_store_dword %0, %1, off sc0 sc1" :: "v"(p), "v"(v) : "memory");
}
DEV unsigned ld_flag(const unsigned* p) {
    unsigned v;
    asm volatile("global_load_dword %0, %1, off sc0 sc1\n\ts_waitcnt vmcnt(0)"
                 : "=v"(v) : "v"(p) : "memory");
    return v;
}
DEV void vmcnt0() { asm volatile("s_waitcnt vmcnt(0)" ::: "memory"); }

// wave 0 polls n (pow2) flags at 128B stride until all >= tgt, then an
// agent-acquire fence (buffer_inv) makes subsequent PLAIN loads cold-miss
// to the coherence point (stale-L2-proof). Other waves park at the barrier.
DEV void wait_flags(const unsigned* f, int n, unsigned tgt) {
    if (threadIdx.x < 64) {
        const unsigned* p = f + (threadIdx.x & (n - 1)) * 32;
        while (true) {
            unsigned v = ld_flag(p);
            if (__all((int)(v >= tgt))) break;
            __builtin_amdgcn_s_sleep(1);
        }
        __builtin_amdgcn_fence(__ATOMIC_ACQUIRE, "agent");
    }
    __syncthreads();
}

// ---------------- weight fp32 -> bf16 conversion ----------------
struct CvtArgs {
    const float* src[7];
    __bf16* dst[7];
    int n[7];
};
__global__ void cvt_weights(CvtArgs a) {
    for (int s = 0; s < 7; ++s) {
        const float* sp = a.src[s];
        __bf16* dp = a.dst[s];
        int n = a.n[s];
        for (int i = blockIdx.x * blockDim.x + threadIdx.x; i < n; i += gridDim.x * blockDim.x)
            dp[i] = (__bf16)sp[i];
    }
}

// ---------------- phase 1: weight-stationary recurrence --------------------
// 192 blocks x 256 threads, 8 groups x 64 batch rows. r = bid>>3: r<8 Z-block
// (hid+z, col-split 32), r>=8 G-block (gates, col-split 32). Weights in LDS.
// h'/hid/z exchanged through out[b][t] bytes [2048,4096) via sc0sc1 WT stores
// (data at coherence point once vmcnt=0, THEN flag). Flags are PER-GROUP.
// Readers: flag poll + agent-acquire fence, then plain pipelined loads.
__global__ __launch_bounds__(256, 1) void phase1c(
    const float* __restrict__ eps,
    const float* __restrict__ b1,  const float* __restrict__ bloc,
    const float* __restrict__ bscale, const float* __restrict__ bih,
    const float* __restrict__ bhh, const float* __restrict__ h0,
    const __bf16* __restrict__ wW1,   const __bf16* __restrict__ wWloc,
    const __bf16* __restrict__ wWscale, const __bf16* __restrict__ wWih,
    const __bf16* __restrict__ wWhh,
    __bf16* __restrict__ h0buf,     // [512][512] bf16 (t=0 h source)
    unsigned* __restrict__ flags,   // per group: 4KB (A:16, B:8, C:8 slots x 128B)
    char* __restrict__ outb)        // out as bytes; row (b*TT+t)*4096
{
    __shared__ __bf16 lds[75776];   // 148 KB

    const int tid  = threadIdx.x;
    const int w    = tid >> 6;
    const int lane = tid & 63;
    const int r16  = lane & 15;
    const int g4   = lane >> 4;
    const int g    = blockIdx.x & 7;
    const int r    = blockIdx.x >> 3;
    unsigned* gfl   = flags + g * 1024;     // 4 KB per group
    unsigned* flagA = gfl;
    unsigned* flagB = gfl + 16 * 32;
    unsigned* flagC = gfl + 24 * 32;
    const int rowW  = g * 64 + w * 16;   // wave row base
    const int rowB0 = g * 64;            // block row base

    auto stage = [&](const __bf16* src, __bf16* dst, int R, int C) {
        int chunks = R * C / 8;
        for (int ch = tid; ch < chunks; ch += 256) {
            int row = ch / (C / 8), cc = (ch % (C / 8)) * 8;
            bf16x8 v = *(const bf16x8*)(src + (size_t)row * C + cc);
            *(bf16x8*)(dst + ((row * C + cc) ^ ((row & 7) << 3))) = v;
        }
    };

    if (r < 8) {
        // ================= Z-block =================
        stage(wW1     + (size_t)(r * 32) * 512, lds,         32, 512);  // 32 KB
        stage(wWloc   + (size_t)(r * 32) * 256, lds + 16384, 32, 256);  // 16 KB
        stage(wWscale + (size_t)(r * 32) * 256, lds + 24576, 32, 256);  // 16 KB
        __bf16* bounce = lds + 32768;   // [64][32]
        const int zc0 = r * 32;
        float bb1[2], bbl[2], bbs[2];
        #pragma unroll
        for (int tt = 0; tt < 2; ++tt) {
            int c = zc0 + tt * 16 + r16;
            bb1[tt] = b1[c]; bbl[tt] = bloc[c]; bbs[tt] = bscale[c];
        }
        __syncthreads();

        for (int t = 0; t < TT; ++t) {
            // eps prefetch (independent of barriers)
            float ev[2][4];
            #pragma unroll
            for (int tt = 0; tt < 2; ++tt)
                #pragma unroll
                for (int i = 0; i < 4; ++i) {
                    int row = rowW + 4 * g4 + i;
                    ev[tt][i] = __builtin_nontemporal_load(
                        eps + ((size_t)row * TT + t) * DZ + zc0 + tt * 16 + r16);
                }
            wait_flags(flagA, 16, t + 1);
            const __bf16* hp = (t == 0)
                ? (h0buf + (size_t)(rowW + r16) * 512 + g4 * 8)
                : (const __bf16*)(outb + ((size_t)(rowW + r16) * TT + (t - 1)) * 4096 + 2048) + g4 * 8;
            // hid = relu(h @ W1^T + b1), own 32 cols
            f32x4 acc0 = {0,0,0,0}, acc1 = {0,0,0,0};
            #pragma unroll
            for (int kk = 0; kk < 16; ++kk) {
                bf16x8 a = *(const bf16x8*)(hp + kk * 32);
                int l0 = r16, l1 = 16 + r16;
                acc0 = mfma16(a, *(const bf16x8*)(lds + ((l0 * 512 + kk * 32 + g4 * 8) ^ ((l0 & 7) << 3))), acc0);
                acc1 = mfma16(a, *(const bf16x8*)(lds + ((l1 * 512 + kk * 32 + g4 * 8) ^ ((l1 & 7) << 3))), acc1);
            }
            #pragma unroll
            for (int tt = 0; tt < 2; ++tt) {
                f32x4 ac = tt ? acc1 : acc0;
                #pragma unroll
                for (int i = 0; i < 4; ++i) {
                    int lr = w * 16 + 4 * g4 + i;
                    bounce[lr * 32 + tt * 16 + r16] = (__bf16)fmaxf(ac[i] + bb1[tt], 0.0f);
                }
            }
            __syncthreads();
            {   // packed write-through: 1 dwordx4 per thread
                int lr = tid >> 2, cc = (tid & 3) * 8;
                bf16x8 v = *(const bf16x8*)(bounce + lr * 32 + cc);
                st16_wt(outb + ((size_t)(rowB0 + lr) * TT + t) * 4096 + 3072 + (zc0 + cc) * 2, v);
                vmcnt0();
            }
            __syncthreads();
            if (tid == 0) st_flag(flagB + r * 32, t + 1);
            wait_flags(flagB, 8, t + 1);
            // z = zloc + softplus(zscale) * eps, own 32 cols (K = all 256 hid)
            const __bf16* qp = (const __bf16*)(outb + ((size_t)(rowW + r16) * TT + t) * 4096 + 3072) + g4 * 8;
            f32x4 aL0 = {0,0,0,0}, aL1 = {0,0,0,0}, aS0 = {0,0,0,0}, aS1 = {0,0,0,0};
            #pragma unroll
            for (int kk = 0; kk < 8; ++kk) {
                bf16x8 a = *(const bf16x8*)(qp + kk * 32);
                int l0 = r16, l1 = 16 + r16;
                int s0 = (l0 * 256 + kk * 32 + g4 * 8) ^ ((l0 & 7) << 3);
                int s1 = (l1 * 256 + kk * 32 + g4 * 8) ^ ((l1 & 7) << 3);
                aL0 = mfma16(a, *(const bf16x8*)(lds + 16384 + s0), aL0);
                aL1 = mfma16(a, *(const bf16x8*)(lds + 16384 + s1), aL1);
                aS0 = mfma16(a, *(const bf16x8*)(lds + 24576 + s0), aS0);
                aS1 = mfma16(a, *(const bf16x8*)(lds + 24576 + s1), aS1);
            }
            #pragma unroll
            for (int tt = 0; tt < 2; ++tt) {
                f32x4 L = tt ? aL1 : aL0, S = tt ? aS1 : aS0;
                #pragma unroll
                for (int i = 0; i < 4; ++i) {
                    int lr = w * 16 + 4 * g4 + i;
                    float z = (L[i] + bbl[tt]) + softplusf(S[i] + bbs[tt]) * ev[tt][i];
                    bounce[lr * 32 + tt * 16 + r16] = (__bf16)z;
                }
            }
            __syncthreads();
            {
                int lr = tid >> 2, cc = (tid & 3) * 8;
                bf16x8 v = *(const bf16x8*)(bounce + lr * 32 + cc);
                st16_wt(outb + ((size_t)(rowB0 + lr) * TT + t) * 4096 + 3584 + (zc0 + cc) * 2, v);
                vmcnt0();
            }
            __syncthreads();
            if (tid == 0) st_flag(flagC + r * 32, t + 1);
        }
    } else {
        // ================= G-block =================
        const int c0 = (r - 8) * 32;
        for (int gg = 0; gg < 3; ++gg) {
            stage(wWhh + (size_t)(512 * gg + c0) * 512, lds + gg * 16384, 32, 512);          // 96 KB
            stage(wWih + (size_t)(512 * gg + c0) * 256, lds + 49152 + gg * 8192, 32, 256);   // 48 KB
        }
        __bf16* bounce = lds + 73728;   // [64][32]
        float bI[3][2], bH[3][2];
        #pragma unroll
        for (int gg = 0; gg < 3; ++gg)
            #pragma unroll
            for (int tt = 0; tt < 2; ++tt) {
                int col = 512 * gg + c0 + tt * 16 + r16;
                bI[gg][tt] = bih[col];
                bH[gg][tt] = bhh[col];
            }
        float hreg[2][4];
        #pragma unroll
        for (int tt = 0; tt < 2; ++tt) {
            int col = c0 + tt * 16 + r16;
            float v = h0[col];
            #pragma unroll
            for (int i = 0; i < 4; ++i) {
                hreg[tt][i] = v;
                int row = rowW + 4 * g4 + i;
                unsigned short u = __builtin_bit_cast(unsigned short, (__bf16)v);
                st2_wt(h0buf + (size_t)row * 512 + col, u);
            }
        }
        vmcnt0();
        __syncthreads();
        if (tid == 0) st_flag(flagA + (r - 8) * 32, 1);

        for (int t = 0; t < TT; ++t) {
            wait_flags(flagA, 16, t + 1);
            const __bf16* hp = (t == 0)
                ? (h0buf + (size_t)(rowW + r16) * 512 + g4 * 8)
                : (const __bf16*)(outb + ((size_t)(rowW + r16) * TT + (t - 1)) * 4096 + 2048) + g4 * 8;
            // gh = h @ Whh_slice^T  (j = gate*2 + tt)
            f32x4 gh[6];
            #pragma unroll
            for (int j = 0; j < 6; ++j) gh[j] = (f32x4){0,0,0,0};
            #pragma unroll
            for (int kk = 0; kk < 16; ++kk) {
                bf16x8 a = *(const bf16x8*)(hp + kk * 32);
                #pragma unroll
                for (int j = 0; j < 6; ++j) {
                    int gg = j >> 1, lr = (j & 1) * 16 + r16;
                    gh[j] = mfma16(a, *(const bf16x8*)(lds + gg * 16384 +
                              ((lr * 512 + kk * 32 + g4 * 8) ^ ((lr & 7) << 3))), gh[j]);
                }
            }
            wait_flags(flagC, 8, t + 1);
            // gi = z @ Wih_slice^T
            const __bf16* zp = (const __bf16*)(outb + ((size_t)(rowW + r16) * TT + t) * 4096 + 3584) + g4 * 8;
            f32x4 gi[6];
            #pragma unroll
            for (int j = 0; j < 6; ++j) gi[j] = (f32x4){0,0,0,0};
            #pragma unroll
            for (int kk = 0; kk < 8; ++kk) {
                bf16x8 a = *(const bf16x8*)(zp + kk * 32);
                #pragma unroll
                for (int j = 0; j < 6; ++j) {
                    int gg = j >> 1, lr = (j & 1) * 16 + r16;
                    gi[j] = mfma16(a, *(const bf16x8*)(lds + 49152 + gg * 8192 +
                              ((lr * 256 + kk * 32 + g4 * 8) ^ ((lr & 7) << 3))), gi[j]);
                }
            }
            // gates + h'
            #pragma unroll
            for (int tt = 0; tt < 2; ++tt) {
                #pragma unroll
                for (int i = 0; i < 4; ++i) {
                    float rr = sigf(gi[0 + tt][i] + bI[0][tt] + gh[0 + tt][i] + bH[0][tt]);
                    float uu = sigf(gi[2 + tt][i] + bI[1][tt] + gh[2 + tt][i] + bH[1][tt]);
                    float nn = tanhf_(gi[4 + tt][i] + bI[2][tt] + rr * (gh[4 + tt][i] + bH[2][tt]));
                    float hv = (1.0f - uu) * nn + uu * hreg[tt][i];
                    hreg[tt][i] = hv;
                    int lr = w * 16 + 4 * g4 + i;
                    bounce[lr * 32 + tt * 16 + r16] = (__bf16)hv;
                }
            }
            __syncthreads();
            {   // packed write-through h' (also phase-2 input)
                int lr = tid >> 2, cc = (tid & 3) * 8;
                bf16x8 v = *(const bf16x8*)(bounce + lr * 32 + cc);
                st16_wt(outb + ((size_t)(rowB0 + lr) * TT + t) * 4096 + 2048 + (c0 + cc) * 2, v);
                vmcnt0();
            }
            __syncthreads();
            if (tid == 0) st_flag(flagA + (r - 8) * 32, t + 2);
        }
    }
}

// ---------------- phase 2: emitter (fully parallel over B*T) ----------------
// Reads bf16 h' stash from out-row bytes [2048,3072); overwrites full rows.
__global__ __launch_bounds__(256, 3) void phase2(
    const float* __restrict__ db1, const float* __restrict__ db2,
    const __bf16* __restrict__ W1, const __bf16* __restrict__ W2,
    float* __restrict__ out)
{
    __shared__ __bf16 hS  [32 * 512];   // 32 KB, swizzled
    __shared__ __bf16 hid2[32 * 256];   // 16 KB, swizzled

    const int tid  = threadIdx.x;
    const int w    = tid >> 6;
    const int lane = tid & 63;
    const int r16  = lane & 15;
    const int g4   = lane >> 4;
    const size_t row0 = (size_t)blockIdx.x * 32;

    #pragma unroll
    for (int it = 0; it < 8; ++it) {
        int chunk = it * 256 + tid;      // 2048 chunks of 8 bf16
        int row = chunk >> 6;
        int cc  = (chunk & 63) * 8;
        bf16x8 v = __builtin_nontemporal_load(
            (const bf16x8*)((const char*)out + (row0 + row) * 4096 + 2048 + cc * 2));
        *(bf16x8*)(hS + ((row * 512 + cc) ^ ((row & 7) << 3))) = v;
    }
    __syncthreads();

    {   // hid2 = relu(h @ dxW1^T + b1)   [32 x 256], K=512
        f32x4 acc[2][4];
        #pragma unroll
        for (int rt = 0; rt < 2; ++rt)
            #pragma unroll
            for (int ct = 0; ct < 4; ++ct) acc[rt][ct] = (f32x4){0,0,0,0};
        const __bf16* pB[4];
        #pragma unroll
        for (int ct = 0; ct < 4; ++ct)
            pB[ct] = W1 + (w * 64 + 16 * ct + r16) * 512 + g4 * 8;
        #pragma unroll
        for (int kk = 0; kk < 16; ++kk) {
            bf16x8 a[2];
            #pragma unroll
            for (int rt = 0; rt < 2; ++rt) {
                int row = rt * 16 + r16;
                a[rt] = *(const bf16x8*)(hS + ((row * 512 + kk * 32 + g4 * 8) ^ ((row & 7) << 3)));
            }
            #pragma unroll
            for (int ct = 0; ct < 4; ++ct) {
                bf16x8 b = *(const bf16x8*)(pB[ct] + kk * 32);
                acc[0][ct] = mfma16(a[0], b, acc[0][ct]);
                acc[1][ct] = mfma16(a[1], b, acc[1][ct]);
            }
        }
        #pragma unroll
        for (int ct = 0; ct < 4; ++ct) {
            int col = w * 64 + 16 * ct + r16;
            float bias = db1[col];
            #pragma unroll
            for (int rt = 0; rt < 2; ++rt)
                #pragma unroll
                for (int i = 0; i < 4; ++i) {
                    int row = rt * 16 + g4 * 4 + i;
                    hid2[(row * 256 + col) ^ ((row & 7) << 3)] =
                        (__bf16)fmaxf(acc[rt][ct][i] + bias, 0.0f);
                }
        }
    }
    __syncthreads();

    #pragma unroll
    for (int c = 0; c < 4; ++c) {   // x = sigmoid(hid2 @ dxW2^T + b2) [32 x 1024]
        f32x4 acc[2][4];
        #pragma unroll
        for (int rt = 0; rt < 2; ++rt)
            #pragma unroll
            for (int ct = 0; ct < 4; ++ct) acc[rt][ct] = (f32x4){0,0,0,0};
        const __bf16* pB[4];
        #pragma unroll
        for (int ct = 0; ct < 4; ++ct)
            pB[ct] = W2 + (w * 256 + c * 64 + 16 * ct + r16) * 256 + g4 * 8;
        #pragma unroll
        for (int kk = 0; kk < 8; ++kk) {
            bf16x8 a[2];
            #pragma unroll
            for (int rt = 0; rt < 2; ++rt) {
                int row = rt * 16 + r16;
                a[rt] = *(const bf16x8*)(hid2 + ((row * 256 + kk * 32 + g4 * 8) ^ ((row & 7) << 3)));
            }
            #pragma unroll
            for (int ct = 0; ct < 4; ++ct) {
                bf16x8 b = *(const bf16x8*)(pB[ct] + kk * 32);
                acc[0][ct] = mfma16(a[0], b, acc[0][ct]);
                acc[1][ct] = mfma16(a[1], b, acc[1][ct]);
            }
        }
        #pragma unroll
        for (int ct = 0; ct < 4; ++ct) {
            int col = w * 256 + c * 64 + 16 * ct + r16;
            float bias = db2[col];
            #pragma unroll
            for (int rt = 0; rt < 2; ++rt)
                #pragma unroll
                for (int i = 0; i < 4; ++i) {
                    int row = rt * 16 + g4 * 4 + i;
                    __builtin_nontemporal_store(sigf(acc[rt][ct][i] + bias),
                                                out + (row0 + row) * DX + col);
                }
        }
    }
}

// ---------------- launch ----------------
extern "C" void kernel_launch(void* const* d_in, const int* in_sizes, int n_in,
                              void* d_out, int out_size, void* d_ws, size_t ws_size,
                              hipStream_t stream) {
    const float* eps       = (const float*)d_in[0];
    const float* dz_W1     = (const float*)d_in[1];
    const float* dz_b1     = (const float*)d_in[2];
    const float* dz_Wloc   = (const float*)d_in[3];
    const float* dz_bloc   = (const float*)d_in[4];
    const float* dz_Wscale = (const float*)d_in[5];
    const float* dz_bscale = (const float*)d_in[6];
    const float* gru_Wih   = (const float*)d_in[7];
    const float* gru_Whh   = (const float*)d_in[8];
    const float* gru_bih   = (const float*)d_in[9];
    const float* gru_bhh   = (const float*)d_in[10];
    const float* dx_W1     = (const float*)d_in[11];
    const float* dx_b1     = (const float*)d_in[12];
    const float* dx_W2     = (const float*)d_in[13];
    const float* dx_b2     = (const float*)d_in[14];
    const float* h0        = (const float*)d_in[15];
    float* out = (float*)d_out;
    char* ws = (char*)d_ws;

    __bf16* wW1     = (__bf16*)(ws + 0);        // 256x512
    __bf16* wWloc   = (__bf16*)(ws + 262144);   // 256x256
    __bf16* wWscale = (__bf16*)(ws + 393216);   // 256x256
    __bf16* wWih    = (__bf16*)(ws + 524288);   // 1536x256
    __bf16* wWhh    = (__bf16*)(ws + 1310720);  // 1536x512
    __bf16* wdxW1   = (__bf16*)(ws + 2883584);  // 256x512
    __bf16* wdxW2   = (__bf16*)(ws + 3145728);  // 1024x256
    __bf16* h0buf   = (__bf16*)(ws + 3670016);  // 512x512 bf16 = 512 KB
    unsigned* flags = (unsigned*)(ws + 4194304); // 8 groups x 4 KB = 32 KB

    hipMemsetAsync(flags, 0, 32768, stream);

    CvtArgs ca;
    ca.src[0] = dz_W1;     ca.dst[0] = wW1;     ca.n[0] = 256 * 512;
    ca.src[1] = dz_Wloc;   ca.dst[1] = wWloc;   ca.n[1] = 256 * 256;
    ca.src[2] = dz_Wscale; ca.dst[2] = wWscale; ca.n[2] = 256 * 256;
    ca.src[3] = gru_Wih;   ca.dst[3] = wWih;    ca.n[3] = 1536 * 256;
    ca.src[4] = gru_Whh;   ca.dst[4] = wWhh;    ca.n[4] = 1536 * 512;
    ca.src[5] = dx_W1;     ca.dst[5] = wdxW1;   ca.n[5] = 256 * 512;
    ca.src[6] = dx_W2;     ca.dst[6] = wdxW2;   ca.n[6] = 1024 * 256;

    cvt_weights<<<1024, 256, 0, stream>>>(ca);
    phase1c<<<192, 256, 0, stream>>>(eps, dz_b1, dz_bloc, dz_bscale,
                                     gru_bih, gru_bhh, h0,
                                     wW1, wWloc, wWscale, wWih, wWhh,
                                     h0buf, flags, (char*)out);
    phase2<<<(BB * TT) / 32, 256, 0, stream>>>(dx_b1, dx_b2, wdxW1, wdxW2, out);
}

// Round 6
// 3225.959 us; speedup vs baseline: 9.6932x; 1.1950x over previous
//
#include <hip/hip_runtime.h>
#include <hip/hip_bf16.h>

#define DEV __device__ __forceinline__

typedef __bf16 bf16x8 __attribute__((ext_vector_type(8)));
typedef float  f32x4  __attribute__((ext_vector_type(4)));

constexpr int BB  = 512;   // batch
constexpr int TT  = 256;   // time steps
constexpr int DX  = 1024;
constexpr int DZ  = 256;
constexpr int DH  = 512;

DEV f32x4 mfma16(bf16x8 a, bf16x8 b, f32x4 c) {
    return __builtin_amdgcn_mfma_f32_16x16x32_bf16(a, b, c, 0, 0, 0);
}
DEV float sigf(float x) { return 1.0f / (1.0f + __expf(-x)); }
DEV float tanhf_(float x) {
    float e = __expf(-2.0f * fabsf(x));
    float r = (1.0f - e) / (1.0f + e);
    return copysignf(r, x);
}
DEV float softplusf(float x) {
    float m = fmaxf(x, 0.0f);
    return m + __logf(__expf(x - m) + __expf(-m));
}

// ---- device-coherent (sc0 sc1) ops: bypass L1/L2, talk to coherence point ----
DEV void st16_wt(void* p, bf16x8 v) {
    asm volatile("global_store_dwordx4 %0, %1, off sc0 sc1" :: "v"(p), "v"(v) : "memory");
}
DEV void st_flag(unsigned* p, unsigned v) {
    asm volatile("global_store_dword %0, %1, off sc0 sc1" :: "v"(p), "v"(v) : "memory");
}
DEV unsigned ld_flag(const unsigned* p) {
    unsigned v;
    asm volatile("global_load_dword %0, %1, off sc0 sc1\n\ts_waitcnt vmcnt(0)"
                 : "=v"(v) : "v"(p) : "memory");
    return v;
}
// coherent data load: ISSUE only (no waitcnt) -- batch then VMCNT0 once
#define CC_LOAD(dst, p) \
    asm volatile("global_load_dwordx4 %0, %1, off sc0 sc1" : "=v"(dst) : "v"(p))
#define VMCNT0 do { \
    asm volatile("s_waitcnt vmcnt(0)" ::: "memory"); \
    __builtin_amdgcn_sched_barrier(0); } while (0)

// wave 0 polls n (pow2) flag slots (128B stride) until all >= tgt. No fence:
// data reads use sc0sc1 loads (same coherence path the flags themselves use).
DEV void wait_flags(const unsigned* f, int n, unsigned tgt) {
    if (threadIdx.x < 64) {
        const unsigned* p = f + (threadIdx.x & (n - 1)) * 32;
        while (true) {
            unsigned v = ld_flag(p);
            if (__all((int)(v >= tgt))) break;
            __builtin_amdgcn_s_sleep(1);
        }
    }
    __syncthreads();
}

// ---------------- weight fp32 -> bf16 conversion + h0 broadcast staging ------
struct CvtArgs {
    const float* src[7];
    __bf16* dst[7];
    int n[7];
};
__global__ void cvt_weights(CvtArgs a, const float* h0, __bf16* h0buf) {
    int idx = blockIdx.x * blockDim.x + threadIdx.x;
    int stride = gridDim.x * blockDim.x;
    for (int s = 0; s < 7; ++s) {
        const float* sp = a.src[s];
        __bf16* dp = a.dst[s];
        int n = a.n[s];
        for (int i = idx; i < n; i += stride) dp[i] = (__bf16)sp[i];
    }
    // h0buf[row][col] = bf16(h0[col]); coherent for phase1c via dispatch boundary
    for (int i = idx; i < 512 * 512; i += stride) h0buf[i] = (__bf16)h0[i & 511];
}

// ---------------- phase 1: weight-stationary recurrence --------------------
// 192 blocks x 256 threads, 8 groups x 64 batch rows. r = bid>>3: r<8 Z-block
// (hid+z, col-split 32), r>=8 G-block (gates, col-split 32). Weights in LDS.
// Exchange via out[b][t] bytes [2048,4096): h' 1KB | hid 512B | z 512B.
// Writers: sc0sc1 WT stores -> vmcnt0 -> flag. Readers: flag poll -> sc0sc1
// coherent loads (no fences, L2 never invalidated).
__global__ __launch_bounds__(256, 1) void phase1c(
    const float* __restrict__ eps,
    const float* __restrict__ b1,  const float* __restrict__ bloc,
    const float* __restrict__ bscale, const float* __restrict__ bih,
    const float* __restrict__ bhh,
    const __bf16* __restrict__ wW1,   const __bf16* __restrict__ wWloc,
    const __bf16* __restrict__ wWscale, const __bf16* __restrict__ wWih,
    const __bf16* __restrict__ wWhh,
    const __bf16* __restrict__ h0buf,   // [512][512] bf16, prefilled
    unsigned* __restrict__ flags,       // per group 4KB: A:16 | B:8 | C:8 x 128B
    char* __restrict__ outb)            // out bytes; row (b*TT+t)*4096
{
    __shared__ __bf16 lds[75776];   // 148 KB

    const int tid  = threadIdx.x;
    const int w    = tid >> 6;
    const int lane = tid & 63;
    const int r16  = lane & 15;
    const int g4   = lane >> 4;
    const int g    = blockIdx.x & 7;
    const int r    = blockIdx.x >> 3;
    unsigned* gfl   = flags + g * 1024;
    unsigned* flagA = gfl;
    unsigned* flagB = gfl + 16 * 32;
    unsigned* flagC = gfl + 24 * 32;
    const int rowW  = g * 64 + w * 16;
    const int rowB0 = g * 64;

    auto stage = [&](const __bf16* src, __bf16* dst, int R, int C) {
        int chunks = R * C / 8;
        for (int ch = tid; ch < chunks; ch += 256) {
            int row = ch / (C / 8), cc = (ch % (C / 8)) * 8;
            bf16x8 v = *(const bf16x8*)(src + (size_t)row * C + cc);
            *(bf16x8*)(dst + ((row * C + cc) ^ ((row & 7) << 3))) = v;
        }
    };

    if (r < 8) {
        // ================= Z-block =================
        stage(wW1     + (size_t)(r * 32) * 512, lds,         32, 512);
        stage(wWloc   + (size_t)(r * 32) * 256, lds + 16384, 32, 256);
        stage(wWscale + (size_t)(r * 32) * 256, lds + 24576, 32, 256);
        __bf16* bounce = lds + 32768;   // [64][32]
        const int zc0 = r * 32;
        float bb1[2], bbl[2], bbs[2];
        #pragma unroll
        for (int tt = 0; tt < 2; ++tt) {
            int c = zc0 + tt * 16 + r16;
            bb1[tt] = b1[c]; bbl[tt] = bloc[c]; bbs[tt] = bscale[c];
        }
        __syncthreads();

        for (int t = 0; t < TT; ++t) {
            float ev[2][4];
            #pragma unroll
            for (int tt = 0; tt < 2; ++tt)
                #pragma unroll
                for (int i = 0; i < 4; ++i) {
                    int row = rowW + 4 * g4 + i;
                    ev[tt][i] = __builtin_nontemporal_load(
                        eps + ((size_t)row * TT + t) * DZ + zc0 + tt * 16 + r16);
                }
            if (t) wait_flags(flagA, 16, t);
            const char* hp = (t == 0)
                ? (const char*)(h0buf + (size_t)(rowW + r16) * 512) + g4 * 16
                : outb + ((size_t)(rowW + r16) * TT + (t - 1)) * 4096 + 2048 + g4 * 16;
            bf16x8 hv[16];
            #pragma unroll
            for (int kk = 0; kk < 16; ++kk) CC_LOAD(hv[kk], hp + kk * 64);
            VMCNT0;
            // hid = relu(h @ W1^T + b1), own 32 cols
            f32x4 acc0 = {0,0,0,0}, acc1 = {0,0,0,0};
            #pragma unroll
            for (int kk = 0; kk < 16; ++kk) {
                int l0 = r16, l1 = 16 + r16;
                acc0 = mfma16(hv[kk], *(const bf16x8*)(lds + ((l0 * 512 + kk * 32 + g4 * 8) ^ ((l0 & 7) << 3))), acc0);
                acc1 = mfma16(hv[kk], *(const bf16x8*)(lds + ((l1 * 512 + kk * 32 + g4 * 8) ^ ((l1 & 7) << 3))), acc1);
            }
            #pragma unroll
            for (int tt = 0; tt < 2; ++tt) {
                f32x4 ac = tt ? acc1 : acc0;
                #pragma unroll
                for (int i = 0; i < 4; ++i) {
                    int lr = w * 16 + 4 * g4 + i;
                    bounce[lr * 32 + tt * 16 + r16] = (__bf16)fmaxf(ac[i] + bb1[tt], 0.0f);
                }
            }
            __syncthreads();
            {
                int lr = tid >> 2, cc = (tid & 3) * 8;
                bf16x8 v = *(const bf16x8*)(bounce + lr * 32 + cc);
                st16_wt(outb + ((size_t)(rowB0 + lr) * TT + t) * 4096 + 3072 + (zc0 + cc) * 2, v);
                VMCNT0;
            }
            __syncthreads();
            if (tid == 0) st_flag(flagB + r * 32, t + 1);
            wait_flags(flagB, 8, t + 1);
            // z = zloc + softplus(zscale) * eps (K = all 256 hid cols)
            const char* qp = outb + ((size_t)(rowW + r16) * TT + t) * 4096 + 3072 + g4 * 16;
            bf16x8 qv[8];
            #pragma unroll
            for (int kk = 0; kk < 8; ++kk) CC_LOAD(qv[kk], qp + kk * 64);
            VMCNT0;
            f32x4 aL0 = {0,0,0,0}, aL1 = {0,0,0,0}, aS0 = {0,0,0,0}, aS1 = {0,0,0,0};
            #pragma unroll
            for (int kk = 0; kk < 8; ++kk) {
                int l0 = r16, l1 = 16 + r16;
                int s0 = (l0 * 256 + kk * 32 + g4 * 8) ^ ((l0 & 7) << 3);
                int s1 = (l1 * 256 + kk * 32 + g4 * 8) ^ ((l1 & 7) << 3);
                aL0 = mfma16(qv[kk], *(const bf16x8*)(lds + 16384 + s0), aL0);
                aL1 = mfma16(qv[kk], *(const bf16x8*)(lds + 16384 + s1), aL1);
                aS0 = mfma16(qv[kk], *(const bf16x8*)(lds + 24576 + s0), aS0);
                aS1 = mfma16(qv[kk], *(const bf16x8*)(lds + 24576 + s1), aS1);
            }
            #pragma unroll
            for (int tt = 0; tt < 2; ++tt) {
                f32x4 L = tt ? aL1 : aL0, S = tt ? aS1 : aS0;
                #pragma unroll
                for (int i = 0; i < 4; ++i) {
                    int lr = w * 16 + 4 * g4 + i;
                    float z = (L[i] + bbl[tt]) + softplusf(S[i] + bbs[tt]) * ev[tt][i];
                    bounce[lr * 32 + tt * 16 + r16] = (__bf16)z;
                }
            }
            __syncthreads();
            {
                int lr = tid >> 2, cc = (tid & 3) * 8;
                bf16x8 v = *(const bf16x8*)(bounce + lr * 32 + cc);
                st16_wt(outb + ((size_t)(rowB0 + lr) * TT + t) * 4096 + 3584 + (zc0 + cc) * 2, v);
                VMCNT0;
            }
            __syncthreads();
            if (tid == 0) st_flag(flagC + r * 32, t + 1);
        }
    } else {
        // ================= G-block =================
        const int c0 = (r - 8) * 32;
        for (int gg = 0; gg < 3; ++gg) {
            stage(wWhh + (size_t)(512 * gg + c0) * 512, lds + gg * 16384, 32, 512);
            stage(wWih + (size_t)(512 * gg + c0) * 256, lds + 49152 + gg * 8192, 32, 256);
        }
        __bf16* bounce = lds + 73728;   // [64][32]
        float bI[3][2], bH[3][2];
        #pragma unroll
        for (int gg = 0; gg < 3; ++gg)
            #pragma unroll
            for (int tt = 0; tt < 2; ++tt) {
                int col = 512 * gg + c0 + tt * 16 + r16;
                bI[gg][tt] = bih[col];
                bH[gg][tt] = bhh[col];
            }
        float hreg[2][4];
        #pragma unroll
        for (int tt = 0; tt < 2; ++tt) {
            float v = (float)h0buf[c0 + tt * 16 + r16];
            #pragma unroll
            for (int i = 0; i < 4; ++i) hreg[tt][i] = v;
        }
        __syncthreads();

        for (int t = 0; t < TT; ++t) {
            if (t) wait_flags(flagA, 16, t);
            const char* hp = (t == 0)
                ? (const char*)(h0buf + (size_t)(rowW + r16) * 512) + g4 * 16
                : outb + ((size_t)(rowW + r16) * TT + (t - 1)) * 4096 + 2048 + g4 * 16;
            bf16x8 hv[16];
            #pragma unroll
            for (int kk = 0; kk < 16; ++kk) CC_LOAD(hv[kk], hp + kk * 64);
            VMCNT0;
            // gh = h @ Whh_slice^T  (j = gate*2 + tt)
            f32x4 gh[6];
            #pragma unroll
            for (int j = 0; j < 6; ++j) gh[j] = (f32x4){0,0,0,0};
            #pragma unroll
            for (int kk = 0; kk < 16; ++kk) {
                #pragma unroll
                for (int j = 0; j < 6; ++j) {
                    int gg = j >> 1, lr = (j & 1) * 16 + r16;
                    gh[j] = mfma16(hv[kk], *(const bf16x8*)(lds + gg * 16384 +
                              ((lr * 512 + kk * 32 + g4 * 8) ^ ((lr & 7) << 3))), gh[j]);
                }
            }
            wait_flags(flagC, 8, t + 1);
            const char* zp = outb + ((size_t)(rowW + r16) * TT + t) * 4096 + 3584 + g4 * 16;
            bf16x8 zv[8];
            #pragma unroll
            for (int kk = 0; kk < 8; ++kk) CC_LOAD(zv[kk], zp + kk * 64);
            VMCNT0;
            // gi = z @ Wih_slice^T
            f32x4 gi[6];
            #pragma unroll
            for (int j = 0; j < 6; ++j) gi[j] = (f32x4){0,0,0,0};
            #pragma unroll
            for (int kk = 0; kk < 8; ++kk) {
                #pragma unroll
                for (int j = 0; j < 6; ++j) {
                    int gg = j >> 1, lr = (j & 1) * 16 + r16;
                    gi[j] = mfma16(zv[kk], *(const bf16x8*)(lds + 49152 + gg * 8192 +
                              ((lr * 256 + kk * 32 + g4 * 8) ^ ((lr & 7) << 3))), gi[j]);
                }
            }
            // gates + h'
            #pragma unroll
            for (int tt = 0; tt < 2; ++tt) {
                #pragma unroll
                for (int i = 0; i < 4; ++i) {
                    float rr = sigf(gi[0 + tt][i] + bI[0][tt] + gh[0 + tt][i] + bH[0][tt]);
                    float uu = sigf(gi[2 + tt][i] + bI[1][tt] + gh[2 + tt][i] + bH[1][tt]);
                    float nn = tanhf_(gi[4 + tt][i] + bI[2][tt] + rr * (gh[4 + tt][i] + bH[2][tt]));
                    float hv2 = (1.0f - uu) * nn + uu * hreg[tt][i];
                    hreg[tt][i] = hv2;
                    int lr = w * 16 + 4 * g4 + i;
                    bounce[lr * 32 + tt * 16 + r16] = (__bf16)hv2;
                }
            }
            __syncthreads();
            {
                int lr = tid >> 2, cc = (tid & 3) * 8;
                bf16x8 v = *(const bf16x8*)(bounce + lr * 32 + cc);
                st16_wt(outb + ((size_t)(rowB0 + lr) * TT + t) * 4096 + 2048 + (c0 + cc) * 2, v);
                VMCNT0;
            }
            __syncthreads();
            if (tid == 0) st_flag(flagA + (r - 8) * 32, t + 1);
        }
    }
}

// ---------------- phase 2: emitter (fully parallel over B*T) ----------------
__global__ __launch_bounds__(256, 3) void phase2(
    const float* __restrict__ db1, const float* __restrict__ db2,
    const __bf16* __restrict__ W1, const __bf16* __restrict__ W2,
    float* __restrict__ out)
{
    __shared__ __bf16 hS  [32 * 512];
    __shared__ __bf16 hid2[32 * 256];

    const int tid  = threadIdx.x;
    const int w    = tid >> 6;
    const int lane = tid & 63;
    const int r16  = lane & 15;
    const int g4   = lane >> 4;
    const size_t row0 = (size_t)blockIdx.x * 32;

    #pragma unroll
    for (int it = 0; it < 8; ++it) {
        int chunk = it * 256 + tid;
        int row = chunk >> 6;
        int cc  = (chunk & 63) * 8;
        bf16x8 v = __builtin_nontemporal_load(
            (const bf16x8*)((const char*)out + (row0 + row) * 4096 + 2048 + cc * 2));
        *(bf16x8*)(hS + ((row * 512 + cc) ^ ((row & 7) << 3))) = v;
    }
    __syncthreads();

    {   // hid2 = relu(h @ dxW1^T + b1)
        f32x4 acc[2][4];
        #pragma unroll
        for (int rt = 0; rt < 2; ++rt)
            #pragma unroll
            for (int ct = 0; ct < 4; ++ct) acc[rt][ct] = (f32x4){0,0,0,0};
        const __bf16* pB[4];
        #pragma unroll
        for (int ct = 0; ct < 4; ++ct)
            pB[ct] = W1 + (w * 64 + 16 * ct + r16) * 512 + g4 * 8;
        #pragma unroll
        for (int kk = 0; kk < 16; ++kk) {
            bf16x8 a[2];
            #pragma unroll
            for (int rt = 0; rt < 2; ++rt) {
                int row = rt * 16 + r16;
                a[rt] = *(const bf16x8*)(hS + ((row * 512 + kk * 32 + g4 * 8) ^ ((row & 7) << 3)));
            }
            #pragma unroll
            for (int ct = 0; ct < 4; ++ct) {
                bf16x8 b = *(const bf16x8*)(pB[ct] + kk * 32);
                acc[0][ct] = mfma16(a[0], b, acc[0][ct]);
                acc[1][ct] = mfma16(a[1], b, acc[1][ct]);
            }
        }
        #pragma unroll
        for (int ct = 0; ct < 4; ++ct) {
            int col = w * 64 + 16 * ct + r16;
            float bias = db1[col];
            #pragma unroll
            for (int rt = 0; rt < 2; ++rt)
                #pragma unroll
                for (int i = 0; i < 4; ++i) {
                    int row = rt * 16 + g4 * 4 + i;
                    hid2[(row * 256 + col) ^ ((row & 7) << 3)] =
                        (__bf16)fmaxf(acc[rt][ct][i] + bias, 0.0f);
                }
        }
    }
    __syncthreads();

    #pragma unroll
    for (int c = 0; c < 4; ++c) {   // x = sigmoid(hid2 @ dxW2^T + b2)
        f32x4 acc[2][4];
        #pragma unroll
        for (int rt = 0; rt < 2; ++rt)
            #pragma unroll
            for (int ct = 0; ct < 4; ++ct) acc[rt][ct] = (f32x4){0,0,0,0};
        const __bf16* pB[4];
        #pragma unroll
        for (int ct = 0; ct < 4; ++ct)
            pB[ct] = W2 + (w * 256 + c * 64 + 16 * ct + r16) * 256 + g4 * 8;
        #pragma unroll
        for (int kk = 0; kk < 8; ++kk) {
            bf16x8 a[2];
            #pragma unroll
            for (int rt = 0; rt < 2; ++rt) {
                int row = rt * 16 + r16;
                a[rt] = *(const bf16x8*)(hid2 + ((row * 256 + kk * 32 + g4 * 8) ^ ((row & 7) << 3)));
            }
            #pragma unroll
            for (int ct = 0; ct < 4; ++ct) {
                bf16x8 b = *(const bf16x8*)(pB[ct] + kk * 32);
                acc[0][ct] = mfma16(a[0], b, acc[0][ct]);
                acc[1][ct] = mfma16(a[1], b, acc[1][ct]);
            }
        }
        #pragma unroll
        for (int ct = 0; ct < 4; ++ct) {
            int col = w * 256 + c * 64 + 16 * ct + r16;
            float bias = db2[col];
            #pragma unroll
            for (int rt = 0; rt < 2; ++rt)
                #pragma unroll
                for (int i = 0; i < 4; ++i) {
                    int row = rt * 16 + g4 * 4 + i;
                    __builtin_nontemporal_store(sigf(acc[rt][ct][i] + bias),
                                                out + (row0 + row) * DX + col);
                }
        }
    }
}

// ---------------- launch ----------------
extern "C" void kernel_launch(void* const* d_in, const int* in_sizes, int n_in,
                              void* d_out, int out_size, void* d_ws, size_t ws_size,
                              hipStream_t stream) {
    const float* eps       = (const float*)d_in[0];
    const float* dz_W1     = (const float*)d_in[1];
    const float* dz_b1     = (const float*)d_in[2];
    const float* dz_Wloc   = (const float*)d_in[3];
    const float* dz_bloc   = (const float*)d_in[4];
    const float* dz_Wscale = (const float*)d_in[5];
    const float* dz_bscale = (const float*)d_in[6];
    const float* gru_Wih   = (const float*)d_in[7];
    const float* gru_Whh   = (const float*)d_in[8];
    const float* gru_bih   = (const float*)d_in[9];
    const float* gru_bhh   = (const float*)d_in[10];
    const float* dx_W1     = (const float*)d_in[11];
    const float* dx_b1     = (const float*)d_in[12];
    const float* dx_W2     = (const float*)d_in[13];
    const float* dx_b2     = (const float*)d_in[14];
    const float* h0        = (const float*)d_in[15];
    float* out = (float*)d_out;
    char* ws = (char*)d_ws;

    __bf16* wW1     = (__bf16*)(ws + 0);
    __bf16* wWloc   = (__bf16*)(ws + 262144);
    __bf16* wWscale = (__bf16*)(ws + 393216);
    __bf16* wWih    = (__bf16*)(ws + 524288);
    __bf16* wWhh    = (__bf16*)(ws + 1310720);
    __bf16* wdxW1   = (__bf16*)(ws + 2883584);
    __bf16* wdxW2   = (__bf16*)(ws + 3145728);
    __bf16* h0buf   = (__bf16*)(ws + 3670016);  // 512x512 bf16
    unsigned* flags = (unsigned*)(ws + 4194304); // 8 groups x 4 KB

    hipMemsetAsync(flags, 0, 32768, stream);

    CvtArgs ca;
    ca.src[0] = dz_W1;     ca.dst[0] = wW1;     ca.n[0] = 256 * 512;
    ca.src[1] = dz_Wloc;   ca.dst[1] = wWloc;   ca.n[1] = 256 * 256;
    ca.src[2] = dz_Wscale; ca.dst[2] = wWscale; ca.n[2] = 256 * 256;
    ca.src[3] = gru_Wih;   ca.dst[3] = wWih;    ca.n[3] = 1536 * 256;
    ca.src[4] = gru_Whh;   ca.dst[4] = wWhh;    ca.n[4] = 1536 * 512;
    ca.src[5] = dx_W1;     ca.dst[5] = wdxW1;   ca.n[5] = 256 * 512;
    ca.src[6] = dx_W2;     ca.dst[6] = wdxW2;   ca.n[6] = 1024 * 256;

    cvt_weights<<<1024, 256, 0, stream>>>(ca, h0, h0buf);
    phase1c<<<192, 256, 0, stream>>>(eps, dz_b1, dz_bloc, dz_bscale,
                                     gru_bih, gru_bhh,
                                     wW1, wWloc, wWscale, wWih, wWhh,
                                     h0buf, flags, (char*)out);
    phase2<<<(BB * TT) / 32, 256, 0, stream>>>(dx_b1, dx_b2, wdxW1, wdxW2, out);
}

// Round 7
// 2818.932 us; speedup vs baseline: 11.0928x; 1.1444x over previous
//
#include <hip/hip_runtime.h>
#include <hip/hip_bf16.h>

#define DEV __device__ __forceinline__

typedef __bf16 bf16x8 __attribute__((ext_vector_type(8)));
typedef float  f32x4  __attribute__((ext_vector_type(4)));

constexpr int BB  = 512;   // batch
constexpr int TT  = 256;   // time steps
constexpr int DX  = 1024;
constexpr int DZ  = 256;
constexpr int DH  = 512;

DEV f32x4 mfma16(bf16x8 a, bf16x8 b, f32x4 c) {
    return __builtin_amdgcn_mfma_f32_16x16x32_bf16(a, b, c, 0, 0, 0);
}
DEV float sigf(float x) { return 1.0f / (1.0f + __expf(-x)); }
DEV float tanhf_(float x) {
    float e = __expf(-2.0f * fabsf(x));
    float r = (1.0f - e) / (1.0f + e);
    return copysignf(r, x);
}
DEV float softplusf(float x) {
    float m = fmaxf(x, 0.0f);
    return m + __logf(__expf(x - m) + __expf(-m));
}

// ---- device-coherent (sc0 sc1) ops: bypass L1/L2, talk to coherence point ----
DEV void st16_wt(void* p, bf16x8 v) {
    asm volatile("global_store_dwordx4 %0, %1, off sc0 sc1" :: "v"(p), "v"(v) : "memory");
}
DEV void st_flag(unsigned* p, unsigned v) {
    asm volatile("global_store_dword %0, %1, off sc0 sc1" :: "v"(p), "v"(v) : "memory");
}
DEV unsigned ld_flag(const unsigned* p) {
    unsigned v;
    asm volatile("global_load_dword %0, %1, off sc0 sc1\n\ts_waitcnt vmcnt(0)"
                 : "=v"(v) : "v"(p) : "memory");
    return v;
}
// coherent data load: ISSUE only (no waitcnt) -- batch then VMCNT0 once
#define CC_LOAD(dst, p) \
    asm volatile("global_load_dwordx4 %0, %1, off sc0 sc1" : "=v"(dst) : "v"(p))
#define VMCNT0 do { \
    asm volatile("s_waitcnt vmcnt(0)" ::: "memory"); \
    __builtin_amdgcn_sched_barrier(0); } while (0)
#define LGKM0 do { \
    asm volatile("s_waitcnt lgkmcnt(0)" ::: "memory"); \
    __builtin_amdgcn_sched_barrier(0); } while (0)

// per-WAVE wait: poll nslots (pow2) flags for wave index wv; hard spin
// (iterations are paced by the flag-load RTT). No fence needed: data reads
// are sc0sc1 (same coherence path as the flags).
DEV void wave_wait(const unsigned* base, int nslots, int wv, unsigned tgt) {
    const int lane = threadIdx.x & 63;
    const unsigned* p = base + (((lane & (nslots - 1)) * 4 + wv) * 32);
    while (true) {
        unsigned v = ld_flag(p);
        if (__all((int)(v >= tgt))) break;
    }
}

// ---------------- weight fp32 -> bf16 conversion + h0 broadcast staging ------
struct CvtArgs {
    const float* src[7];
    __bf16* dst[7];
    int n[7];
};
__global__ void cvt_weights(CvtArgs a, const float* h0, __bf16* h0buf) {
    int idx = blockIdx.x * blockDim.x + threadIdx.x;
    int stride = gridDim.x * blockDim.x;
    for (int s = 0; s < 7; ++s) {
        const float* sp = a.src[s];
        __bf16* dp = a.dst[s];
        int n = a.n[s];
        for (int i = idx; i < n; i += stride) dp[i] = (__bf16)sp[i];
    }
    for (int i = idx; i < 512 * 512; i += stride) h0buf[i] = (__bf16)h0[i & 511];
}

// ---------------- phase 1: weight-stationary recurrence, wave-decoupled -----
// 192 blocks x 256 threads, 8 groups x 64 batch rows. r = bid>>3: r<8 Z-block
// (hid+z, col-split 32), r>=8 G-block (gates, col-split 32). Weights in LDS.
// EACH WAVE owns 16 batch rows end-to-end: no __syncthreads in the loop,
// per-wave LDS bounce (wave-internal DS ordering), per-(block,wave) flags so
// producers signal after 16 rows and consumers wait only row-matched data.
// Exchange via out[b][t] bytes [2048,4096): h' 1KB | hid 512B | z 512B,
// sc0sc1 write-through; readers use batched sc0sc1 loads. Flags monotone t+1.
__global__ __launch_bounds__(256, 1) void phase1c(
    const float* __restrict__ eps,
    const float* __restrict__ b1,  const float* __restrict__ bloc,
    const float* __restrict__ bscale, const float* __restrict__ bih,
    const float* __restrict__ bhh,
    const __bf16* __restrict__ wW1,   const __bf16* __restrict__ wWloc,
    const __bf16* __restrict__ wWscale, const __bf16* __restrict__ wWih,
    const __bf16* __restrict__ wWhh,
    const __bf16* __restrict__ h0buf,   // [512][512] bf16, prefilled
    unsigned* __restrict__ flags,       // per group 16KB: A 64 | B 32 | C 32 slots x128B
    char* __restrict__ outb)            // out bytes; row (b*TT+t)*4096
{
    __shared__ __bf16 lds[75776];   // 148 KB

    const int tid  = threadIdx.x;
    const int w    = tid >> 6;
    const int lane = tid & 63;
    const int r16  = lane & 15;
    const int g4   = lane >> 4;
    const int g    = blockIdx.x & 7;
    const int r    = blockIdx.x >> 3;
    unsigned* gfl   = flags + g * 4096;      // 16 KB per group
    unsigned* flagA = gfl;                   // 64 slots (16 G-blocks x 4 waves)
    unsigned* flagB = gfl + 2048;            // 32 slots (8 Z x 4)
    unsigned* flagC = gfl + 3072;            // 32 slots (8 Z x 4)
    const int rowW  = g * 64 + w * 16;       // this wave's batch-row base

    auto stage = [&](const __bf16* src, __bf16* dst, int R, int C) {
        int chunks = R * C / 8;
        for (int ch = tid; ch < chunks; ch += 256) {
            int row = ch / (C / 8), cc = (ch % (C / 8)) * 8;
            bf16x8 v = *(const bf16x8*)(src + (size_t)row * C + cc);
            *(bf16x8*)(dst + ((row * C + cc) ^ ((row & 7) << 3))) = v;
        }
    };

    if (r < 8) {
        // ================= Z-block =================
        stage(wW1     + (size_t)(r * 32) * 512, lds,         32, 512);
        stage(wWloc   + (size_t)(r * 32) * 256, lds + 16384, 32, 256);
        stage(wWscale + (size_t)(r * 32) * 256, lds + 24576, 32, 256);
        __bf16* wb = lds + 32768 + w * 512;   // per-wave bounce [16][32]
        const int zc0 = r * 32;
        float bb1[2], bbl[2], bbs[2];
        #pragma unroll
        for (int tt = 0; tt < 2; ++tt) {
            int c = zc0 + tt * 16 + r16;
            bb1[tt] = b1[c]; bbl[tt] = bloc[c]; bbs[tt] = bscale[c];
        }
        __syncthreads();   // weights staged (only barrier)

        for (int t = 0; t < TT; ++t) {
            float ev[2][4];
            #pragma unroll
            for (int tt = 0; tt < 2; ++tt)
                #pragma unroll
                for (int i = 0; i < 4; ++i) {
                    int row = rowW + 4 * g4 + i;
                    ev[tt][i] = __builtin_nontemporal_load(
                        eps + ((size_t)row * TT + t) * DZ + zc0 + tt * 16 + r16);
                }
            if (t) wave_wait(flagA, 16, w, t);
            const char* hp = (t == 0)
                ? (const char*)(h0buf + (size_t)(rowW + r16) * 512) + g4 * 16
                : outb + ((size_t)(rowW + r16) * TT + (t - 1)) * 4096 + 2048 + g4 * 16;
            bf16x8 hv[16];
            #pragma unroll
            for (int kk = 0; kk < 16; ++kk) CC_LOAD(hv[kk], hp + kk * 64);
            VMCNT0;
            // hid = relu(h @ W1^T + b1), own 32 cols
            f32x4 acc0 = {0,0,0,0}, acc1 = {0,0,0,0};
            #pragma unroll
            for (int kk = 0; kk < 16; ++kk) {
                int l0 = r16, l1 = 16 + r16;
                acc0 = mfma16(hv[kk], *(const bf16x8*)(lds + ((l0 * 512 + kk * 32 + g4 * 8) ^ ((l0 & 7) << 3))), acc0);
                acc1 = mfma16(hv[kk], *(const bf16x8*)(lds + ((l1 * 512 + kk * 32 + g4 * 8) ^ ((l1 & 7) << 3))), acc1);
            }
            #pragma unroll
            for (int tt = 0; tt < 2; ++tt) {
                f32x4 ac = tt ? acc1 : acc0;
                #pragma unroll
                for (int i = 0; i < 4; ++i)
                    wb[(4 * g4 + i) * 32 + tt * 16 + r16] = (__bf16)fmaxf(ac[i] + bb1[tt], 0.0f);
            }
            LGKM0;   // wave-internal: bounce writes done before packed reads
            {
                int rl = lane >> 2, ch = lane & 3;
                bf16x8 v = *(const bf16x8*)(wb + rl * 32 + ch * 8);
                st16_wt(outb + ((size_t)(rowW + rl) * TT + t) * 4096 + 3072 + (zc0 + ch * 8) * 2, v);
            }
            VMCNT0;   // drain WT stores (and eps)
            if (lane == 0) st_flag(flagB + (r * 4 + w) * 32, t + 1);
            wave_wait(flagB, 8, w, t + 1);
            // z = zloc + softplus(zscale) * eps (K = all 256 hid cols)
            const char* qp = outb + ((size_t)(rowW + r16) * TT + t) * 4096 + 3072 + g4 * 16;
            bf16x8 qv[8];
            #pragma unroll
            for (int kk = 0; kk < 8; ++kk) CC_LOAD(qv[kk], qp + kk * 64);
            VMCNT0;
            f32x4 aL0 = {0,0,0,0}, aL1 = {0,0,0,0}, aS0 = {0,0,0,0}, aS1 = {0,0,0,0};
            #pragma unroll
            for (int kk = 0; kk < 8; ++kk) {
                int l0 = r16, l1 = 16 + r16;
                int s0 = (l0 * 256 + kk * 32 + g4 * 8) ^ ((l0 & 7) << 3);
                int s1 = (l1 * 256 + kk * 32 + g4 * 8) ^ ((l1 & 7) << 3);
                aL0 = mfma16(qv[kk], *(const bf16x8*)(lds + 16384 + s0), aL0);
                aL1 = mfma16(qv[kk], *(const bf16x8*)(lds + 16384 + s1), aL1);
                aS0 = mfma16(qv[kk], *(const bf16x8*)(lds + 24576 + s0), aS0);
                aS1 = mfma16(qv[kk], *(const bf16x8*)(lds + 24576 + s1), aS1);
            }
            #pragma unroll
            for (int tt = 0; tt < 2; ++tt) {
                f32x4 L = tt ? aL1 : aL0, S = tt ? aS1 : aS0;
                #pragma unroll
                for (int i = 0; i < 4; ++i) {
                    float z = (L[i] + bbl[tt]) + softplusf(S[i] + bbs[tt]) * ev[tt][i];
                    wb[(4 * g4 + i) * 32 + tt * 16 + r16] = (__bf16)z;
                }
            }
            LGKM0;
            {
                int rl = lane >> 2, ch = lane & 3;
                bf16x8 v = *(const bf16x8*)(wb + rl * 32 + ch * 8);
                st16_wt(outb + ((size_t)(rowW + rl) * TT + t) * 4096 + 3584 + (zc0 + ch * 8) * 2, v);
            }
            VMCNT0;
            if (lane == 0) st_flag(flagC + (r * 4 + w) * 32, t + 1);
        }
    } else {
        // ================= G-block =================
        const int c0 = (r - 8) * 32;
        for (int gg = 0; gg < 3; ++gg) {
            stage(wWhh + (size_t)(512 * gg + c0) * 512, lds + gg * 16384, 32, 512);
            stage(wWih + (size_t)(512 * gg + c0) * 256, lds + 49152 + gg * 8192, 32, 256);
        }
        __bf16* wb = lds + 73728 + w * 512;   // per-wave bounce [16][32]
        float bI[3][2], bH[3][2];
        #pragma unroll
        for (int gg = 0; gg < 3; ++gg)
            #pragma unroll
            for (int tt = 0; tt < 2; ++tt) {
                int col = 512 * gg + c0 + tt * 16 + r16;
                bI[gg][tt] = bih[col];
                bH[gg][tt] = bhh[col];
            }
        float hreg[2][4];
        #pragma unroll
        for (int tt = 0; tt < 2; ++tt) {
            float v = (float)h0buf[c0 + tt * 16 + r16];
            #pragma unroll
            for (int i = 0; i < 4; ++i) hreg[tt][i] = v;
        }
        __syncthreads();   // weights staged (only barrier)

        for (int t = 0; t < TT; ++t) {
            if (t) wave_wait(flagA, 16, w, t);
            const char* hp = (t == 0)
                ? (const char*)(h0buf + (size_t)(rowW + r16) * 512) + g4 * 16
                : outb + ((size_t)(rowW + r16) * TT + (t - 1)) * 4096 + 2048 + g4 * 16;
            bf16x8 hv[16];
            #pragma unroll
            for (int kk = 0; kk < 16; ++kk) CC_LOAD(hv[kk], hp + kk * 64);
            VMCNT0;
            // gh = h @ Whh_slice^T  (j = gate*2 + tt)
            f32x4 gh[6];
            #pragma unroll
            for (int j = 0; j < 6; ++j) gh[j] = (f32x4){0,0,0,0};
            #pragma unroll
            for (int kk = 0; kk < 16; ++kk) {
                #pragma unroll
                for (int j = 0; j < 6; ++j) {
                    int gg = j >> 1, lr = (j & 1) * 16 + r16;
                    gh[j] = mfma16(hv[kk], *(const bf16x8*)(lds + gg * 16384 +
                              ((lr * 512 + kk * 32 + g4 * 8) ^ ((lr & 7) << 3))), gh[j]);
                }
            }
            wave_wait(flagC, 8, w, t + 1);
            const char* zp = outb + ((size_t)(rowW + r16) * TT + t) * 4096 + 3584 + g4 * 16;
            bf16x8 zv[8];
            #pragma unroll
            for (int kk = 0; kk < 8; ++kk) CC_LOAD(zv[kk], zp + kk * 64);
            VMCNT0;
            // gi = z @ Wih_slice^T
            f32x4 gi[6];
            #pragma unroll
            for (int j = 0; j < 6; ++j) gi[j] = (f32x4){0,0,0,0};
            #pragma unroll
            for (int kk = 0; kk < 8; ++kk) {
                #pragma unroll
                for (int j = 0; j < 6; ++j) {
                    int gg = j >> 1, lr = (j & 1) * 16 + r16;
                    gi[j] = mfma16(zv[kk], *(const bf16x8*)(lds + 49152 + gg * 8192 +
                              ((lr * 256 + kk * 32 + g4 * 8) ^ ((lr & 7) << 3))), gi[j]);
                }
            }
            // gates + h'
            #pragma unroll
            for (int tt = 0; tt < 2; ++tt) {
                #pragma unroll
                for (int i = 0; i < 4; ++i) {
                    float rr = sigf(gi[0 + tt][i] + bI[0][tt] + gh[0 + tt][i] + bH[0][tt]);
                    float uu = sigf(gi[2 + tt][i] + bI[1][tt] + gh[2 + tt][i] + bH[1][tt]);
                    float nn = tanhf_(gi[4 + tt][i] + bI[2][tt] + rr * (gh[4 + tt][i] + bH[2][tt]));
                    float hv2 = (1.0f - uu) * nn + uu * hreg[tt][i];
                    hreg[tt][i] = hv2;
                    wb[(4 * g4 + i) * 32 + tt * 16 + r16] = (__bf16)hv2;
                }
            }
            LGKM0;
            {
                int rl = lane >> 2, ch = lane & 3;
                bf16x8 v = *(const bf16x8*)(wb + rl * 32 + ch * 8);
                st16_wt(outb + ((size_t)(rowW + rl) * TT + t) * 4096 + 2048 + (c0 + ch * 8) * 2, v);
            }
            VMCNT0;
            if (lane == 0) st_flag(flagA + ((r - 8) * 4 + w) * 32, t + 1);
        }
    }
}

// ---------------- phase 2: emitter (fully parallel over B*T) ----------------
__global__ __launch_bounds__(256, 3) void phase2(
    const float* __restrict__ db1, const float* __restrict__ db2,
    const __bf16* __restrict__ W1, const __bf16* __restrict__ W2,
    float* __restrict__ out)
{
    __shared__ __bf16 hS  [32 * 512];
    __shared__ __bf16 hid2[32 * 256];

    const int tid  = threadIdx.x;
    const int w    = tid >> 6;
    const int lane = tid & 63;
    const int r16  = lane & 15;
    const int g4   = lane >> 4;
    const size_t row0 = (size_t)blockIdx.x * 32;

    #pragma unroll
    for (int it = 0; it < 8; ++it) {
        int chunk = it * 256 + tid;
        int row = chunk >> 6;
        int cc  = (chunk & 63) * 8;
        bf16x8 v = __builtin_nontemporal_load(
            (const bf16x8*)((const char*)out + (row0 + row) * 4096 + 2048 + cc * 2));
        *(bf16x8*)(hS + ((row * 512 + cc) ^ ((row & 7) << 3))) = v;
    }
    __syncthreads();

    {   // hid2 = relu(h @ dxW1^T + b1)
        f32x4 acc[2][4];
        #pragma unroll
        for (int rt = 0; rt < 2; ++rt)
            #pragma unroll
            for (int ct = 0; ct < 4; ++ct) acc[rt][ct] = (f32x4){0,0,0,0};
        const __bf16* pB[4];
        #pragma unroll
        for (int ct = 0; ct < 4; ++ct)
            pB[ct] = W1 + (w * 64 + 16 * ct + r16) * 512 + g4 * 8;
        #pragma unroll
        for (int kk = 0; kk < 16; ++kk) {
            bf16x8 a[2];
            #pragma unroll
            for (int rt = 0; rt < 2; ++rt) {
                int row = rt * 16 + r16;
                a[rt] = *(const bf16x8*)(hS + ((row * 512 + kk * 32 + g4 * 8) ^ ((row & 7) << 3)));
            }
            #pragma unroll
            for (int ct = 0; ct < 4; ++ct) {
                bf16x8 b = *(const bf16x8*)(pB[ct] + kk * 32);
                acc[0][ct] = mfma16(a[0], b, acc[0][ct]);
                acc[1][ct] = mfma16(a[1], b, acc[1][ct]);
            }
        }
        #pragma unroll
        for (int ct = 0; ct < 4; ++ct) {
            int col = w * 64 + 16 * ct + r16;
            float bias = db1[col];
            #pragma unroll
            for (int rt = 0; rt < 2; ++rt)
                #pragma unroll
                for (int i = 0; i < 4; ++i) {
                    int row = rt * 16 + g4 * 4 + i;
                    hid2[(row * 256 + col) ^ ((row & 7) << 3)] =
                        (__bf16)fmaxf(acc[rt][ct][i] + bias, 0.0f);
                }
        }
    }
    __syncthreads();

    #pragma unroll
    for (int c = 0; c < 4; ++c) {   // x = sigmoid(hid2 @ dxW2^T + b2)
        f32x4 acc[2][4];
        #pragma unroll
        for (int rt = 0; rt < 2; ++rt)
            #pragma unroll
            for (int ct = 0; ct < 4; ++ct) acc[rt][ct] = (f32x4){0,0,0,0};
        const __bf16* pB[4];
        #pragma unroll
        for (int ct = 0; ct < 4; ++ct)
            pB[ct] = W2 + (w * 256 + c * 64 + 16 * ct + r16) * 256 + g4 * 8;
        #pragma unroll
        for (int kk = 0; kk < 8; ++kk) {
            bf16x8 a[2];
            #pragma unroll
            for (int rt = 0; rt < 2; ++rt) {
                int row = rt * 16 + r16;
                a[rt] = *(const bf16x8*)(hid2 + ((row * 256 + kk * 32 + g4 * 8) ^ ((row & 7) << 3)));
            }
            #pragma unroll
            for (int ct = 0; ct < 4; ++ct) {
                bf16x8 b = *(const bf16x8*)(pB[ct] + kk * 32);
                acc[0][ct] = mfma16(a[0], b, acc[0][ct]);
                acc[1][ct] = mfma16(a[1], b, acc[1][ct]);
            }
        }
        #pragma unroll
        for (int ct = 0; ct < 4; ++ct) {
            int col = w * 256 + c * 64 + 16 * ct + r16;
            float bias = db2[col];
            #pragma unroll
            for (int rt = 0; rt < 2; ++rt)
                #pragma unroll
                for (int i = 0; i < 4; ++i) {
                    int row = rt * 16 + g4 * 4 + i;
                    __builtin_nontemporal_store(sigf(acc[rt][ct][i] + bias),
                                                out + (row0 + row) * DX + col);
                }
        }
    }
}

// ---------------- launch ----------------
extern "C" void kernel_launch(void* const* d_in, const int* in_sizes, int n_in,
                              void* d_out, int out_size, void* d_ws, size_t ws_size,
                              hipStream_t stream) {
    const float* eps       = (const float*)d_in[0];
    const float* dz_W1     = (const float*)d_in[1];
    const float* dz_b1     = (const float*)d_in[2];
    const float* dz_Wloc   = (const float*)d_in[3];
    const float* dz_bloc   = (const float*)d_in[4];
    const float* dz_Wscale = (const float*)d_in[5];
    const float* dz_bscale = (const float*)d_in[6];
    const float* gru_Wih   = (const float*)d_in[7];
    const float* gru_Whh   = (const float*)d_in[8];
    const float* gru_bih   = (const float*)d_in[9];
    const float* gru_bhh   = (const float*)d_in[10];
    const float* dx_W1     = (const float*)d_in[11];
    const float* dx_b1     = (const float*)d_in[12];
    const float* dx_W2     = (const float*)d_in[13];
    const float* dx_b2     = (const float*)d_in[14];
    const float* h0        = (const float*)d_in[15];
    float* out = (float*)d_out;
    char* ws = (char*)d_ws;

    __bf16* wW1     = (__bf16*)(ws + 0);
    __bf16* wWloc   = (__bf16*)(ws + 262144);
    __bf16* wWscale = (__bf16*)(ws + 393216);
    __bf16* wWih    = (__bf16*)(ws + 524288);
    __bf16* wWhh    = (__bf16*)(ws + 1310720);
    __bf16* wdxW1   = (__bf16*)(ws + 2883584);
    __bf16* wdxW2   = (__bf16*)(ws + 3145728);
    __bf16* h0buf   = (__bf16*)(ws + 3670016);   // 512x512 bf16
    unsigned* flags = (unsigned*)(ws + 4194304); // 8 groups x 16 KB = 128 KB

    hipMemsetAsync(flags, 0, 131072, stream);

    CvtArgs ca;
    ca.src[0] = dz_W1;     ca.dst[0] = wW1;     ca.n[0] = 256 * 512;
    ca.src[1] = dz_Wloc;   ca.dst[1] = wWloc;   ca.n[1] = 256 * 256;
    ca.src[2] = dz_Wscale; ca.dst[2] = wWscale; ca.n[2] = 256 * 256;
    ca.src[3] = gru_Wih;   ca.dst[3] = wWih;    ca.n[3] = 1536 * 256;
    ca.src[4] = gru_Whh;   ca.dst[4] = wWhh;    ca.n[4] = 1536 * 512;
    ca.src[5] = dx_W1;     ca.dst[5] = wdxW1;   ca.n[5] = 256 * 512;
    ca.src[6] = dx_W2;     ca.dst[6] = wdxW2;   ca.n[6] = 1024 * 256;

    cvt_weights<<<1024, 256, 0, stream>>>(ca, h0, h0buf);
    phase1c<<<192, 256, 0, stream>>>(eps, dz_b1, dz_bloc, dz_bscale,
                                     gru_bih, gru_bhh,
                                     wW1, wWloc, wWscale, wWih, wWhh,
                                     h0buf, flags, (char*)out);
    phase2<<<(BB * TT) / 32, 256, 0, stream>>>(dx_b1, dx_b2, wdxW1, wdxW2, out);
}